// Round 21
// baseline (154.299 us; speedup 1.0000x reference)
//
#include <hip/hip_runtime.h>
#include <hip/hip_bf16.h>
#include <hip/hip_fp16.h>
#include <cstdint>

static constexpr int NB  = 8;
static constexpr int HH  = 96;
static constexpr int WW  = 96;
static constexpr int NP  = 9216;   // 96*96
static constexpr int NPK = 576;    // 24*24

using bf8 = __attribute__((ext_vector_type(8))) short;
using f4  = __attribute__((ext_vector_type(4))) float;

__device__ __forceinline__ unsigned pack_bf2(float a, float b) {
    __hip_bfloat162 h = __float22bfloat162_rn(make_float2(a, b));
    unsigned u; __builtin_memcpy(&u, &h, 4);
    return u;
}
__device__ __forceinline__ unsigned short f2bfu(float f) {
    __hip_bfloat16 h = __float2bfloat16(f);
    unsigned short u; __builtin_memcpy(&u, &h, 2);
    return u;
}
__device__ __forceinline__ float bf2f(unsigned short u) {
    unsigned v = (unsigned)u << 16;
    float f; __builtin_memcpy(&f, &v, 4);
    return f;
}
__device__ __forceinline__ float bflo(unsigned p) {
    unsigned v = p << 16; float f; __builtin_memcpy(&f, &v, 4); return f;
}
__device__ __forceinline__ float bfhi(unsigned p) {
    unsigned v = p & 0xffff0000u; float f; __builtin_memcpy(&f, &v, 4); return f;
}

// packed-weight segment offsets (uints)
static constexpr int PW_QKV  = 0;       // 192*64
static constexpr int PW_GQ   = 12288;   // 64*64  (scaled 0.25)
static constexpr int PW_GKV  = 16384;   // 128*64
static constexpr int PW_AM1  = 24576;   // 64*32
static constexpr int PW_AM2  = 26624;   // 64*32
static constexpr int PW_PROJ = 28672;   // 128*64
static constexpr int PW_TOTAL= 36864;

// ---------------------------------------------------------------------------
// One-time weight pre-pack (gq segment scaled 0.25).
// ---------------------------------------------------------------------------
__global__ __launch_bounds__(256) void k_packw(
    const float* __restrict__ qkv_w, const float* __restrict__ gq_w,
    const float* __restrict__ gkv_w, const float* __restrict__ am_w1,
    const float* __restrict__ am_w2, const float* __restrict__ proj_w,
    unsigned* __restrict__ pw)
{
    const int idx = blockIdx.x * 256 + threadIdx.x;
    if (idx >= PW_TOTAL) return;
    const float* src; int j2; float sc = 1.0f;
    if (idx < PW_GQ)          { src = qkv_w;  j2 = (idx - PW_QKV) * 2; }
    else if (idx < PW_GKV)    { src = gq_w;   j2 = (idx - PW_GQ) * 2;  sc = 0.25f; }
    else if (idx < PW_AM1)    { src = gkv_w;  j2 = (idx - PW_GKV) * 2; }
    else if (idx < PW_AM2)    { src = am_w1;  j2 = (idx - PW_AM1) * 2; }
    else if (idx < PW_PROJ)   { src = am_w2;  j2 = (idx - PW_AM2) * 2; }
    else                      { src = proj_w; j2 = (idx - PW_PROJ) * 2; }
    pw[idx] = pack_bf2(src[j2] * sc, src[j2 + 1] * sc);
}

// ---------------------------------------------------------------------------
// Merged avgpool + qkv/gq conv launch.
// Blocks 0..2303: avgpool (x -> t_pool, f32); dispatched first, drains under
// the conv blocks.  Blocks 2304..3455: qkvgq (r17 logic, grid flattened).
// ---------------------------------------------------------------------------
__global__ __launch_bounds__(256) void k_pool_qkvgq(
    const float* __restrict__ x, const unsigned* __restrict__ pw,
    const float* __restrict__ qkv_b, const float* __restrict__ gq_b,
    unsigned short* __restrict__ qkv_out,   // bf16 (B,192,NP)
    unsigned short* __restrict__ gq_out,    // bf16 (B,64,NP), pre-scaled 0.25
    float* __restrict__ pool_out)           // f32 (B,128,NPK)
{
    __shared__ __align__(16) unsigned xl[64 * 64];   // 16KB (qkvgq path only)
    const int bid = blockIdx.x;
    const int tid = threadIdx.x;

    if (bid < 2304) {
        // ---- avgpool path ----
        const int idx = bid * 256 + tid;
        int pw4 = idx % 24;
        int t  = idx / 24;
        int ph = t % 24;  t /= 24;
        int c  = t % 128;
        int b  = t / 128;
        const float* ip = x + ((long long)b * 128 + c) * NP + (ph * 4) * WW + pw4 * 4;
        float4 r0 = *(const float4*)(ip);
        float4 r1 = *(const float4*)(ip + WW);
        float4 r2 = *(const float4*)(ip + 2 * WW);
        float4 r3 = *(const float4*)(ip + 3 * WW);
        float s = ((r0.x + r0.y) + (r0.z + r0.w)) + ((r1.x + r1.y) + (r1.z + r1.w))
                + ((r2.x + r2.y) + (r2.z + r2.w)) + ((r3.x + r3.y) + (r3.z + r3.w));
        pool_out[idx] = s * (1.0f / 16.0f);
        return;
    }

    // ---- qkvgq path (flattened) ----
    const int qq   = bid - 2304;
    const int quad = qq % 144, b = qq / 144;
    const int lane = tid & 63, wid = tid >> 6;
    const int arow = lane & 15, agrp = lane >> 4;

    const float* xb = x + (long long)b * 128 * NP + quad * 64;

#pragma unroll
    for (int it = 0; it < 4; ++it) {
        const int task = tid + 256 * it;
        const int cp = task >> 4, pq = task & 15;
        float4 a = *(const float4*)&xb[(long long)(2 * cp) * NP + pq * 4];
        float4 c = *(const float4*)&xb[(long long)(2 * cp + 1) * NP + pq * 4];
        const int cps = cp ^ ((pq & 7) << 2);
        xl[(pq * 4 + 0) * 64 + cps] = pack_bf2(a.x, c.x);
        xl[(pq * 4 + 1) * 64 + cps] = pack_bf2(a.y, c.y);
        xl[(pq * 4 + 2) * 64 + cps] = pack_bf2(a.z, c.z);
        xl[(pq * 4 + 3) * 64 + cps] = pack_bf2(a.w, c.w);
    }
    __syncthreads();

    uint4 breg[4][4];
#pragma unroll
    for (int kt = 0; kt < 4; ++kt)
#pragma unroll
        for (int i = 0; i < 4; ++i) {
            const int px = arow * 4 + i;
            const int cp = (kt * 16 + agrp * 4) ^ ((arow & 7) << 2);
            breg[kt][i] = *(const uint4*)&xl[px * 64 + cp];
        }

    for (int gi = 0; gi < 4; ++gi) {
        const int grp = wid + gi * 4;
        const bool isgq = grp >= 12;
        const int och = (isgq ? grp - 12 : grp) * 16;
        const unsigned* wseg = pw + (isgq ? PW_GQ : PW_QKV);
        const float* bsrc = isgq ? gq_b : qkv_b;
        const float bsc = isgq ? 0.25f : 1.0f;

        bf8 afr[4];
#pragma unroll
        for (int kt = 0; kt < 4; ++kt) {
            uint4 t = *(const uint4*)&wseg[(och + arow) * 64 + kt * 16 + agrp * 4];
            afr[kt] = __builtin_bit_cast(bf8, t);
        }

        f4 acc[4];
#pragma unroll
        for (int i = 0; i < 4; ++i) acc[i] = (f4){0.f, 0.f, 0.f, 0.f};
#pragma unroll
        for (int kt = 0; kt < 4; ++kt)
#pragma unroll
            for (int i = 0; i < 4; ++i)
                acc[i] = __builtin_amdgcn_mfma_f32_16x16x32_bf16(
                    afr[kt], __builtin_bit_cast(bf8, breg[kt][i]), acc[i], 0, 0, 0);

        unsigned short* ob = isgq ? gq_out : qkv_out;
        const int ostride = isgq ? 64 : 192;
#pragma unroll
        for (int r = 0; r < 4; ++r) {
            const int o = och + agrp * 4 + r;
            const float bs = bsrc[o] * bsc;
            const float v0 = acc[0][r] + bs, v1 = acc[1][r] + bs;
            const float v2 = acc[2][r] + bs, v3 = acc[3][r] + bs;
            *(uint2*)&ob[((long long)b * ostride + o) * NP + quad * 64 + arow * 4] =
                make_uint2(pack_bf2(v0, v1), pack_bf2(v2, v3));
        }
    }
}

// ---------------------------------------------------------------------------
// Merged gkv-conv + depthwise launch.
// Blocks 0..47: gkv = conv1x1(pooled) (f32 out), dispatched first.
// Blocks 48..4655: row-tiled depthwise 5x5 (r19 logic, flattened).
// ---------------------------------------------------------------------------
__global__ __launch_bounds__(256) void k_gkv_dw(
    const float* __restrict__ pool_in, const unsigned* __restrict__ pw,
    const float* __restrict__ gkv_b, float* __restrict__ gkv_out,
    const unsigned short* __restrict__ qkv_in, const float* __restrict__ dw_w,
    const float* __restrict__ dw_b, unsigned short* __restrict__ dw_out)
{
    __shared__ __align__(16) float img[36 * WW];   // 13824 B (dwconv path only)
    const int bid = blockIdx.x;
    const int tid = threadIdx.x;
    const int lane = tid & 63, wid = tid >> 6;

    if (bid < 48) {
        // ---- gkv path: conv1x1 C=128, OT=4, f32 in/out, np=NPK ----
        const int bx = bid % 3, by = (bid / 3) % 2, bz = bid / 6;
        const int arow = lane & 15, agrp = lane >> 4;
        const int obq = by * 64;
        const int quad = bx * 4 + wid;
        if (quad >= 9) return;
        const int p0 = quad * 64 + arow * 4;

        bf8 afr[4][4];
#pragma unroll
        for (int ot = 0; ot < 4; ++ot)
#pragma unroll
            for (int kt = 0; kt < 4; ++kt) {
                uint4 t = *(const uint4*)&pw[PW_GKV + (obq + ot * 16 + arow) * 64 + kt * 16 + agrp * 4];
                afr[ot][kt] = __builtin_bit_cast(bf8, t);
            }

        const float* x0f = pool_in + (long long)bz * 128 * NPK;

        f4 acc[4][4];
#pragma unroll
        for (int i = 0; i < 4; ++i)
#pragma unroll
            for (int ot = 0; ot < 4; ++ot) acc[i][ot] = (f4){0.f, 0.f, 0.f, 0.f};

#pragma unroll
        for (int kt = 0; kt < 4; ++kt) {
            const long long cbase = kt * 32 + agrp * 8;
            int uu[4][4];
#pragma unroll
            for (int jj = 0; jj < 4; ++jj) {
                float4 a0 = *(const float4*)&x0f[(cbase + 2 * jj) * NPK + p0];
                float4 a1 = *(const float4*)&x0f[(cbase + 2 * jj + 1) * NPK + p0];
                uu[0][jj] = (int)pack_bf2(a0.x, a1.x);
                uu[1][jj] = (int)pack_bf2(a0.y, a1.y);
                uu[2][jj] = (int)pack_bf2(a0.z, a1.z);
                uu[3][jj] = (int)pack_bf2(a0.w, a1.w);
            }
#pragma unroll
            for (int i = 0; i < 4; ++i) {
                int4 ti = {uu[i][0], uu[i][1], uu[i][2], uu[i][3]};
                bf8 bfr = __builtin_bit_cast(bf8, ti);
#pragma unroll
                for (int ot = 0; ot < 4; ++ot)
                    acc[i][ot] = __builtin_amdgcn_mfma_f32_16x16x32_bf16(afr[ot][kt], bfr, acc[i][ot], 0, 0, 0);
            }
        }

#pragma unroll
        for (int ot = 0; ot < 4; ++ot) {
#pragma unroll
            for (int r = 0; r < 4; ++r) {
                const int o = obq + ot * 16 + agrp * 4 + r;
                const float bs = gkv_b[o];
                float4 v;
                v.x = acc[0][ot][r] + bs;
                v.y = acc[1][ot][r] + bs;
                v.z = acc[2][ot][r] + bs;
                v.w = acc[3][ot][r] + bs;
                *(float4*)&gkv_out[((long long)bz * 128 + o) * NPK + p0] = v;
            }
        }
        return;
    }

    // ---- dwconv path (flattened: ch fastest, then rt, then b) ----
    const int dbid = bid - 48;
    const int ch = dbid % 192;
    const int rt = (dbid / 192) % 3;
    const int b  = dbid / 576;
    const unsigned short* ip = qkv_in + ((long long)b * 192 + ch) * NP;

    const int gr0 = rt * 32 - 2;
    for (int idx = tid; idx < 864; idx += 256) {
        const int rr = idx / 24, c4 = (idx - rr * 24) * 4;
        const int gr = gr0 + rr;
        float4 f;
        if (gr >= 0 && gr < HH) {
            const uint2 rv = *(const uint2*)&ip[gr * WW + c4];
            f.x = bflo(rv.x); f.y = bfhi(rv.x);
            f.z = bflo(rv.y); f.w = bfhi(rv.y);
        } else {
            f = make_float4(0.f, 0.f, 0.f, 0.f);
        }
        *(float4*)&img[rr * WW + c4] = f;
    }
    __syncthreads();

    const float* wp = dw_w + ch * 25;
    float wr[25];
#pragma unroll
    for (int i = 0; i < 25; ++i) wr[i] = wp[i];
    const float bs = dw_b[ch];

    unsigned short* op = dw_out + ((long long)b * 192 + ch) * NP + rt * 32 * WW;

#pragma unroll
    for (int j = 0; j < 3; ++j) {
        const int q  = tid + 256 * j;
        const int yl = q / 24;
        const int x4 = (q - yl * 24) * 4;
        float o0 = bs, o1 = bs, o2 = bs, o3 = bs;
#pragma unroll
        for (int ky = 0; ky < 5; ++ky) {
            const float* row = &img[(yl + ky) * WW + x4];
            float4 mid = *(const float4*)row;
            float4 lf  = (x4 >= 4)      ? *(const float4*)(row - 4)
                                        : make_float4(0.f, 0.f, 0.f, 0.f);
            float4 rtv = (x4 + 4 < WW)  ? *(const float4*)(row + 4)
                                        : make_float4(0.f, 0.f, 0.f, 0.f);
            const float f0 = lf.z,  f1 = lf.w;
            const float f2 = mid.x, f3 = mid.y, f4v = mid.z, f5 = mid.w;
            const float f6 = rtv.x, f7 = rtv.y;
            const float w0 = wr[ky * 5 + 0], w1 = wr[ky * 5 + 1],
                        w2 = wr[ky * 5 + 2], w3 = wr[ky * 5 + 3],
                        w4 = wr[ky * 5 + 4];
            o0 = fmaf(w0, f0, o0); o0 = fmaf(w1, f1, o0); o0 = fmaf(w2, f2, o0);
            o0 = fmaf(w3, f3, o0); o0 = fmaf(w4, f4v, o0);
            o1 = fmaf(w0, f1, o1); o1 = fmaf(w1, f2, o1); o1 = fmaf(w2, f3, o1);
            o1 = fmaf(w3, f4v, o1); o1 = fmaf(w4, f5, o1);
            o2 = fmaf(w0, f2, o2); o2 = fmaf(w1, f3, o2); o2 = fmaf(w2, f4v, o2);
            o2 = fmaf(w3, f5, o2); o2 = fmaf(w4, f6, o2);
            o3 = fmaf(w0, f3, o3); o3 = fmaf(w1, f4v, o3); o3 = fmaf(w2, f5, o3);
            o3 = fmaf(w3, f6, o3); o3 = fmaf(w4, f7, o3);
        }
        *(uint2*)&op[yl * WW + x4] = make_uint2(pack_bf2(o0, o1), pack_bf2(o2, o3));
    }
}

// ---------------------------------------------------------------------------
// MFMA conv1x1 (proj: bf16 in -> f32 out); weights pre-packed.  OT=2 for TLP.
// ---------------------------------------------------------------------------
template<int C, int OT, int INBF, int OUTBF>
__global__ __launch_bounds__(256) void k_mfma_conv(
    const void* __restrict__ in0v, const unsigned* __restrict__ pw,
    const float* __restrict__ bias, void* __restrict__ outv,
    int np, long long ibs, int storeO)
{
    constexpr int KT = C / 32;
    const int tid  = threadIdx.x;
    const int lane = tid & 63, wid = tid >> 6;
    const int b    = blockIdx.z;
    const int obq  = blockIdx.y * (OT * 16);
    const int arow = lane & 15, agrp = lane >> 4;
    const int nquad = np >> 6;

    bf8 afr[OT][KT];
#pragma unroll
    for (int ot = 0; ot < OT; ++ot)
#pragma unroll
        for (int kt = 0; kt < KT; ++kt) {
            uint4 t = *(const uint4*)&pw[(obq + ot * 16 + arow) * (C / 2) + kt * 16 + agrp * 4];
            afr[ot][kt] = __builtin_bit_cast(bf8, t);
        }

    const float*          x0f = (const float*)in0v          + (long long)b * (INBF ? 0 : ibs);
    const unsigned short* x0h = (const unsigned short*)in0v + (long long)b * (INBF ? ibs : 0);

    const int quad = blockIdx.x * 4 + wid;
    if (quad >= nquad) return;
    const int p0 = quad * 64 + arow * 4;

    f4 acc[4][OT];
#pragma unroll
    for (int i = 0; i < 4; ++i)
#pragma unroll
        for (int ot = 0; ot < OT; ++ot) acc[i][ot] = (f4){0.f, 0.f, 0.f, 0.f};

#pragma unroll
    for (int kt = 0; kt < KT; ++kt) {
        const long long cbase = kt * 32 + agrp * 8;
        int uu[4][4];
#pragma unroll
        for (int jj = 0; jj < 4; ++jj) {
            if (INBF == 0) {
                float4 a0 = *(const float4*)&x0f[(cbase + 2 * jj) * np + p0];
                float4 a1 = *(const float4*)&x0f[(cbase + 2 * jj + 1) * np + p0];
                uu[0][jj] = (int)pack_bf2(a0.x, a1.x);
                uu[1][jj] = (int)pack_bf2(a0.y, a1.y);
                uu[2][jj] = (int)pack_bf2(a0.z, a1.z);
                uu[3][jj] = (int)pack_bf2(a0.w, a1.w);
            } else {
                ushort4 a0 = *(const ushort4*)&x0h[(cbase + 2 * jj) * np + p0];
                ushort4 a1 = *(const ushort4*)&x0h[(cbase + 2 * jj + 1) * np + p0];
                uu[0][jj] = (int)((unsigned)a0.x | ((unsigned)a1.x << 16));
                uu[1][jj] = (int)((unsigned)a0.y | ((unsigned)a1.y << 16));
                uu[2][jj] = (int)((unsigned)a0.z | ((unsigned)a1.z << 16));
                uu[3][jj] = (int)((unsigned)a0.w | ((unsigned)a1.w << 16));
            }
        }
#pragma unroll
        for (int i = 0; i < 4; ++i) {
            int4 ti = {uu[i][0], uu[i][1], uu[i][2], uu[i][3]};
            bf8 bfr = __builtin_bit_cast(bf8, ti);
#pragma unroll
            for (int ot = 0; ot < OT; ++ot)
                acc[i][ot] = __builtin_amdgcn_mfma_f32_16x16x32_bf16(afr[ot][kt], bfr, acc[i][ot], 0, 0, 0);
        }
    }

#pragma unroll
    for (int ot = 0; ot < OT; ++ot) {
#pragma unroll
        for (int r = 0; r < 4; ++r) {
            const int o = obq + ot * 16 + agrp * 4 + r;
            const float bs = bias[o];
            float4 v;
            v.x = acc[0][ot][r] + bs;
            v.y = acc[1][ot][r] + bs;
            v.z = acc[2][ot][r] + bs;
            v.w = acc[3][ot][r] + bs;
            const long long idx = ((long long)b * storeO + o) * np + p0;
            if (OUTBF == 0) {
                *(float4*)&((float*)outv)[idx] = v;
            } else {
                *(uint2*)&((unsigned short*)outv)[idx] =
                    make_uint2(pack_bf2(v.x, v.y), pack_bf2(v.z, v.w));
            }
        }
    }
}

// ---------------------------------------------------------------------------
// Merged am + attention kernel (r20, unchanged; verified 71.1 µs).
// ---------------------------------------------------------------------------
__global__ __launch_bounds__(256) void k_am_attn(
    const unsigned short* __restrict__ dw, const unsigned* __restrict__ pw,
    const float* __restrict__ b1v, const float* __restrict__ b2v,
    const unsigned short* __restrict__ q, const float* __restrict__ kv,
    unsigned short* __restrict__ hilo)
{
    __shared__ __align__(16) char smem[53760];
    const int bid = blockIdx.x;
    const int tid = threadIdx.x;
    const int lane = tid & 63, wid = tid >> 6;

    if (bid < 576) {
        // ================= am path (half-quad per wave) =================
        uint2* abuf = (uint2*)smem;
        const int arow = lane & 15, agrp = lane >> 4;

        const int hqi = bid * 4 + wid;
        const int b   = hqi / 288;
        const int t288 = hqi % 288;
        const int quad = t288 >> 1, half = t288 & 1;
        const int pp = quad * 64 + arow * 4 + half * 2;

        bf8 afr1[4][2], afr2[4][2];
#pragma unroll
        for (int ot = 0; ot < 4; ++ot)
#pragma unroll
            for (int kt = 0; kt < 2; ++kt) {
                uint4 t1 = *(const uint4*)&pw[PW_AM1 + (ot * 16 + arow) * 32 + kt * 16 + agrp * 4];
                uint4 t2 = *(const uint4*)&pw[PW_AM2 + (ot * 16 + arow) * 32 + kt * 16 + agrp * 4];
                afr1[ot][kt] = __builtin_bit_cast(bf8, t1);
                afr2[ot][kt] = __builtin_bit_cast(bf8, t2);
            }

        const unsigned short* xq = dw + (long long)b * (192ll * NP);
        const unsigned short* xk = xq + 64ll * NP;
        const unsigned short* xv = xq + 128ll * NP;

        f4 acc1[2][4];
#pragma unroll
        for (int i = 0; i < 2; ++i)
#pragma unroll
            for (int ot = 0; ot < 4; ++ot) acc1[i][ot] = (f4){0.f, 0.f, 0.f, 0.f};

#pragma unroll
        for (int kt = 0; kt < 2; ++kt) {
            const long long cbase = kt * 32 + agrp * 8;
            int uu[2][4];
#pragma unroll
            for (int jj = 0; jj < 4; ++jj) {
                ushort2 a0 = *(const ushort2*)&xq[(cbase + 2 * jj) * NP + pp];
                ushort2 a1 = *(const ushort2*)&xq[(cbase + 2 * jj + 1) * NP + pp];
                ushort2 y0 = *(const ushort2*)&xk[(cbase + 2 * jj) * NP + pp];
                ushort2 y1 = *(const ushort2*)&xk[(cbase + 2 * jj + 1) * NP + pp];
                uu[0][jj] = (int)pack_bf2(bf2f(a0.x) * bf2f(y0.x), bf2f(a1.x) * bf2f(y1.x));
                uu[1][jj] = (int)pack_bf2(bf2f(a0.y) * bf2f(y0.y), bf2f(a1.y) * bf2f(y1.y));
            }
#pragma unroll
            for (int i = 0; i < 2; ++i) {
                int4 ti = {uu[i][0], uu[i][1], uu[i][2], uu[i][3]};
                bf8 bfr = __builtin_bit_cast(bf8, ti);
#pragma unroll
                for (int ot = 0; ot < 4; ++ot)
                    acc1[i][ot] = __builtin_amdgcn_mfma_f32_16x16x32_bf16(afr1[ot][kt], bfr, acc1[i][ot], 0, 0, 0);
            }
        }

#pragma unroll
        for (int i = 0; i < 2; ++i)
#pragma unroll
            for (int ot = 0; ot < 4; ++ot) {
                const int ch0 = ot * 16 + agrp * 4;
                float v0 = acc1[i][ot][0] + b1v[ch0 + 0];
                float v1 = acc1[i][ot][1] + b1v[ch0 + 1];
                float v2 = acc1[i][ot][2] + b1v[ch0 + 2];
                float v3 = acc1[i][ot][3] + b1v[ch0 + 3];
                v0 = v0 / (1.f + __expf(-v0));
                v1 = v1 / (1.f + __expf(-v1));
                v2 = v2 / (1.f + __expf(-v2));
                v3 = v3 / (1.f + __expf(-v3));
                const int c2 = ot * 4 + agrp;
                abuf[wid * 512 + (arow * 2 + i) * 16 + (c2 ^ arow)] =
                    make_uint2(pack_bf2(v0, v1), pack_bf2(v2, v3));
            }

        f4 acc2[2][4];
#pragma unroll
        for (int i = 0; i < 2; ++i)
#pragma unroll
            for (int ot = 0; ot < 4; ++ot) acc2[i][ot] = (f4){0.f, 0.f, 0.f, 0.f};

#pragma unroll
        for (int kt = 0; kt < 2; ++kt) {
            const int bc2 = kt * 8 + agrp * 2;
#pragma unroll
            for (int i = 0; i < 2; ++i) {
                const uint2 rA = abuf[wid * 512 + (arow * 2 + i) * 16 + (bc2 ^ arow)];
                const uint2 rB = abuf[wid * 512 + (arow * 2 + i) * 16 + ((bc2 + 1) ^ arow)];
                int4 ti = make_int4((int)rA.x, (int)rA.y, (int)rB.x, (int)rB.y);
                bf8 bfr = __builtin_bit_cast(bf8, ti);
#pragma unroll
                for (int ot = 0; ot < 4; ++ot)
                    acc2[i][ot] = __builtin_amdgcn_mfma_f32_16x16x32_bf16(afr2[ot][kt], bfr, acc2[i][ot], 0, 0, 0);
            }
        }

#pragma unroll
        for (int ot = 0; ot < 4; ++ot) {
#pragma unroll
            for (int r = 0; r < 4; ++r) {
                const int o = ot * 16 + agrp * 4 + r;
                const float bs = b2v[o];
                ushort2 vv2 = *(const ushort2*)&xv[(long long)o * NP + pp];
                float h0 = tanhf((acc2[0][ot][r] + bs) * 0.25f) * bf2f(vv2.x);
                float h1 = tanhf((acc2[1][ot][r] + bs) * 0.25f) * bf2f(vv2.y);
                *(unsigned*)&hilo[((long long)b * 128 + o) * NP + pp] = pack_bf2(h0, h1);
            }
        }
        return;
    }

    // ================= attn path (r12-exact logic) =================
    int4*  klds4 = (int4*)smem;
    int4*  zlds4 = (int4*)(smem + 18432);
    int4*  vlds4 = (int4*)(smem + 18944);
    uint2* elds2 = (uint2*)(smem + 37376);

    const int flat = bid - 576;
    const int bx = flat % 72, bh = flat / 72;
    const int g = lane >> 4, qi = lane & 15;
    const int b = bh >> 2, h = bh & 3;

    const float* kbase = kv + ((long long)b * 128 + h * 16) * NPK;
    const float* vbase = kv + ((long long)b * 128 + 64 + h * 16) * NPK;

    for (int i = tid; i < 1152; i += 256) {
        const int key = i >> 1, dg = i & 1;
        const float* kp = kbase + (long long)(dg * 8) * NPK + key;
        int4 t;
        t.x = (int)pack_bf2(kp[0],       kp[NPK]);
        t.y = (int)pack_bf2(kp[2 * NPK], kp[3 * NPK]);
        t.z = (int)pack_bf2(kp[4 * NPK], kp[5 * NPK]);
        t.w = (int)pack_bf2(kp[6 * NPK], kp[7 * NPK]);
        klds4[(key >> 4) * 32 + dg * 16 + (key & 15)] = t;
    }
    for (int i = tid; i < 1152; i += 256) {
        const int t = i >> 6, l = i & 63;
        const float* vp = vbase + (long long)(l & 15) * NPK + t * 32 + (l >> 4) * 8;
        float4 a = *(const float4*)vp;
        float4 c = *(const float4*)(vp + 4);
        int4 tt;
        tt.x = (int)pack_bf2(a.x, a.y);
        tt.y = (int)pack_bf2(a.z, a.w);
        tt.z = (int)pack_bf2(c.x, c.y);
        tt.w = (int)pack_bf2(c.z, c.w);
        vlds4[i] = tt;
    }
    if (tid < 32) zlds4[tid] = make_int4(0, 0, 0, 0);
    __syncthreads();

    const int q0 = (bx * 4 + wid) * 32;
    const unsigned short* qcol = q + ((long long)b * 64 + h * 16) * NP + q0 + qi;
    int4 qv[2] = { make_int4(0, 0, 0, 0), make_int4(0, 0, 0, 0) };
    if (g < 2) {
#pragma unroll
        for (int s = 0; s < 2; ++s) {
            const unsigned short* qp = qcol + s * 16 + (long long)(g * 8) * NP;
            qv[s].x = (int)((unsigned)qp[0]          | ((unsigned)qp[(long long)NP]     << 16));
            qv[s].y = (int)((unsigned)qp[2ll * NP]   | ((unsigned)qp[3ll * NP]          << 16));
            qv[s].z = (int)((unsigned)qp[4ll * NP]   | ((unsigned)qp[5ll * NP]          << 16));
            qv[s].w = (int)((unsigned)qp[6ll * NP]   | ((unsigned)qp[7ll * NP]          << 16));
        }
    }

    f4 accp[2] = { (f4){0.f, 0.f, 0.f, 0.f}, (f4){0.f, 0.f, 0.f, 0.f} };
    float den[2] = { 0.f, 0.f };

    auto QKEXP = [&](int k2, int buf) {
#pragma unroll
        for (int tp = 0; tp < 2; ++tp) {
            const int4 kf = (lane < 32) ? klds4[(k2 * 2 + tp) * 32 + lane]
                                        : zlds4[lane & 31];
            const bf8 ka = __builtin_bit_cast(bf8, kf);
#pragma unroll
            for (int s = 0; s < 2; ++s) {
                f4 sa = __builtin_amdgcn_mfma_f32_16x16x32_bf16(
                    ka, __builtin_bit_cast(bf8, qv[s]), (f4){0.f, 0.f, 0.f, 0.f}, 0, 0, 0);
                const float e0 = __expf(sa[0]), e1 = __expf(sa[1]);
                const float e2 = __expf(sa[2]), e3 = __expf(sa[3]);
                den[s] += (e0 + e1) + (e2 + e3);
                elds2[buf * 1024 + wid * 256 + s * 128 + tp * 64 + g * 16 + qi] =
                    make_uint2(pack_bf2(e0, e1), pack_bf2(e2, e3));
            }
        }
    };
    auto PV = [&](int k2, int buf) {
        const bf8 va = __builtin_bit_cast(bf8, vlds4[k2 * 64 + lane]);
#pragma unroll
        for (int s = 0; s < 2; ++s) {
            const int base = buf * 1024 + wid * 256 + s * 128 + (g >> 1) * 64 + (g & 1) * 32 + qi;
            const uint2 r0 = elds2[base];
            const uint2 r1 = elds2[base + 16];
            int4 ti = make_int4((int)r0.x, (int)r0.y, (int)r1.x, (int)r1.y);
            accp[s] = __builtin_amdgcn_mfma_f32_16x16x32_bf16(
                va, __builtin_bit_cast(bf8, ti), accp[s], 0, 0, 0);
        }
    };

    QKEXP(0, 0);
    for (int k2 = 0; k2 < 17; ++k2) {
        QKEXP(k2 + 1, (k2 + 1) & 1);
        PV(k2, k2 & 1);
    }
    PV(17, 1);

#pragma unroll
    for (int s = 0; s < 2; ++s) {
        float d0 = den[s];
        d0 += __shfl_xor(d0, 16, 64);
        d0 += __shfl_xor(d0, 32, 64);
        const float inv = 1.0f / d0;
        unsigned short* op = hilo + ((long long)b * 128 + 64 + h * 16 + g * 4) * NP + q0 + s * 16 + qi;
#pragma unroll
        for (int r = 0; r < 4; ++r)
            op[(long long)r * NP] = f2bfu(accp[s][r] * inv);
    }
}

// ---------------------------------------------------------------------------
extern "C" void kernel_launch(void* const* d_in, const int* in_sizes, int n_in,
                              void* d_out, int out_size, void* d_ws, size_t ws_size,
                              hipStream_t stream)
{
    const float* x      = (const float*)d_in[0];
    const float* qkv_w  = (const float*)d_in[1];
    const float* qkv_b  = (const float*)d_in[2];
    const float* dw_w   = (const float*)d_in[3];
    const float* dw_b   = (const float*)d_in[4];
    const float* am_w1  = (const float*)d_in[5];
    const float* am_b1  = (const float*)d_in[6];
    const float* am_w2  = (const float*)d_in[7];
    const float* am_b2  = (const float*)d_in[8];
    const float* gq_w   = (const float*)d_in[9];
    const float* gq_b   = (const float*)d_in[10];
    const float* gkv_w  = (const float*)d_in[11];
    const float* gkv_b  = (const float*)d_in[12];
    const float* proj_w = (const float*)d_in[13];
    const float* proj_b = (const float*)d_in[14];
    float* out = (float*)d_out;
    char* wsb = (char*)d_ws;

    unsigned short* t_qkv  = (unsigned short*)wsb;
    unsigned short* t_hilo = (unsigned short*)wsb;
    unsigned short* t_dw   = (unsigned short*)(wsb + 28311552);
    unsigned short* t_gq   = (unsigned short*)(wsb + 56623104);
    float*          t_pool = (float*)(wsb + 66060288);
    float*          t_gkv  = (float*)(wsb + 68419584);
    unsigned*       t_pw   = (unsigned*)(wsb + 70778880);

    // 0. pre-pack all conv weights (gq scaled 0.25)
    k_packw<<<dim3((PW_TOTAL + 255) / 256), 256, 0, stream>>>(
        qkv_w, gq_w, gkv_w, am_w1, am_w2, proj_w, t_pw);
    // 1. merged avgpool (blocks 0..2303) + qkv/gq conv (2304..3455)
    k_pool_qkvgq<<<dim3(3456), 256, 0, stream>>>(
        x, t_pw, qkv_b, gq_b, t_qkv, t_gq, t_pool);
    // 2. merged gkv conv (blocks 0..47) + depthwise 5x5 (48..4655)
    k_gkv_dw<<<dim3(4656), 256, 0, stream>>>(
        t_pool, t_pw, gkv_b, t_gkv, t_qkv, dw_w, dw_b, t_dw);
    // 3. merged am (blocks 0..575, half-quad) + attention (576..2879)
    k_am_attn<<<dim3(2880), 256, 0, stream>>>(
        t_dw, t_pw, am_b1, am_b2, t_gq, t_gkv, t_hilo);
    // 4. out = conv1x1(hilo bf16, proj_w), OT=2 for TLP  (f32 out)
    k_mfma_conv<128,2,1,0><<<dim3(36,4,NB), 256, 0, stream>>>(
        t_hilo, t_pw + PW_PROJ, proj_b, out, NP, (long long)128 * NP, 128);
}

// Round 22
// 149.801 us; speedup vs baseline: 1.0300x; 1.0300x over previous
//
#include <hip/hip_runtime.h>
#include <hip/hip_bf16.h>
#include <hip/hip_fp16.h>
#include <cstdint>

static constexpr int NB  = 8;
static constexpr int HH  = 96;
static constexpr int WW  = 96;
static constexpr int NP  = 9216;   // 96*96
static constexpr int NPK = 576;    // 24*24

using bf8 = __attribute__((ext_vector_type(8))) short;
using f4  = __attribute__((ext_vector_type(4))) float;

__device__ __forceinline__ unsigned pack_bf2(float a, float b) {
    __hip_bfloat162 h = __float22bfloat162_rn(make_float2(a, b));
    unsigned u; __builtin_memcpy(&u, &h, 4);
    return u;
}
__device__ __forceinline__ unsigned short f2bfu(float f) {
    __hip_bfloat16 h = __float2bfloat16(f);
    unsigned short u; __builtin_memcpy(&u, &h, 2);
    return u;
}
__device__ __forceinline__ float bf2f(unsigned short u) {
    unsigned v = (unsigned)u << 16;
    float f; __builtin_memcpy(&f, &v, 4);
    return f;
}
__device__ __forceinline__ float bflo(unsigned p) {
    unsigned v = p << 16; float f; __builtin_memcpy(&f, &v, 4); return f;
}
__device__ __forceinline__ float bfhi(unsigned p) {
    unsigned v = p & 0xffff0000u; float f; __builtin_memcpy(&f, &v, 4); return f;
}

// packed-weight segment offsets (uints)
static constexpr int PW_QKV  = 0;       // 192*64
static constexpr int PW_GQ   = 12288;   // 64*64  (scaled 0.25)
static constexpr int PW_GKV  = 16384;   // 128*64
static constexpr int PW_AM1  = 24576;   // 64*32
static constexpr int PW_AM2  = 26624;   // 64*32
static constexpr int PW_PROJ = 28672;   // 128*64
static constexpr int PW_TOTAL= 36864;

// ---------------------------------------------------------------------------
// One-time weight pre-pack (gq segment scaled 0.25).
// ---------------------------------------------------------------------------
__global__ __launch_bounds__(256) void k_packw(
    const float* __restrict__ qkv_w, const float* __restrict__ gq_w,
    const float* __restrict__ gkv_w, const float* __restrict__ am_w1,
    const float* __restrict__ am_w2, const float* __restrict__ proj_w,
    unsigned* __restrict__ pw)
{
    const int idx = blockIdx.x * 256 + threadIdx.x;
    if (idx >= PW_TOTAL) return;
    const float* src; int j2; float sc = 1.0f;
    if (idx < PW_GQ)          { src = qkv_w;  j2 = (idx - PW_QKV) * 2; }
    else if (idx < PW_GKV)    { src = gq_w;   j2 = (idx - PW_GQ) * 2;  sc = 0.25f; }
    else if (idx < PW_AM1)    { src = gkv_w;  j2 = (idx - PW_GKV) * 2; }
    else if (idx < PW_AM2)    { src = am_w1;  j2 = (idx - PW_AM1) * 2; }
    else if (idx < PW_PROJ)   { src = am_w2;  j2 = (idx - PW_AM2) * 2; }
    else                      { src = proj_w; j2 = (idx - PW_PROJ) * 2; }
    pw[idx] = pack_bf2(src[j2] * sc, src[j2 + 1] * sc);
}

// ---------------------------------------------------------------------------
// Fused qkv+gq conv1x1 with LDS-staged x; weights pre-packed. (r20-exact)
// ---------------------------------------------------------------------------
__global__ __launch_bounds__(256) void k_qkvgq(
    const float* __restrict__ x, const unsigned* __restrict__ pw,
    const float* __restrict__ qkv_b, const float* __restrict__ gq_b,
    unsigned short* __restrict__ qkv_out,   // bf16 (B,192,NP)
    unsigned short* __restrict__ gq_out)    // bf16 (B,64,NP), pre-scaled 0.25
{
    __shared__ __align__(16) unsigned xl[64 * 64];   // 16KB
    const int tid  = threadIdx.x;
    const int lane = tid & 63, wid = tid >> 6;
    const int quad = blockIdx.x, b = blockIdx.z;
    const int arow = lane & 15, agrp = lane >> 4;

    const float* xb = x + (long long)b * 128 * NP + quad * 64;

#pragma unroll
    for (int it = 0; it < 4; ++it) {
        const int task = tid + 256 * it;
        const int cp = task >> 4, pq = task & 15;
        float4 a = *(const float4*)&xb[(long long)(2 * cp) * NP + pq * 4];
        float4 c = *(const float4*)&xb[(long long)(2 * cp + 1) * NP + pq * 4];
        const int cps = cp ^ ((pq & 7) << 2);
        xl[(pq * 4 + 0) * 64 + cps] = pack_bf2(a.x, c.x);
        xl[(pq * 4 + 1) * 64 + cps] = pack_bf2(a.y, c.y);
        xl[(pq * 4 + 2) * 64 + cps] = pack_bf2(a.z, c.z);
        xl[(pq * 4 + 3) * 64 + cps] = pack_bf2(a.w, c.w);
    }
    __syncthreads();

    uint4 breg[4][4];
#pragma unroll
    for (int kt = 0; kt < 4; ++kt)
#pragma unroll
        for (int i = 0; i < 4; ++i) {
            const int px = arow * 4 + i;
            const int cp = (kt * 16 + agrp * 4) ^ ((arow & 7) << 2);
            breg[kt][i] = *(const uint4*)&xl[px * 64 + cp];
        }

    for (int gi = 0; gi < 4; ++gi) {
        const int grp = wid + gi * 4;
        const bool isgq = grp >= 12;
        const int och = (isgq ? grp - 12 : grp) * 16;
        const unsigned* wseg = pw + (isgq ? PW_GQ : PW_QKV);
        const float* bsrc = isgq ? gq_b : qkv_b;
        const float bsc = isgq ? 0.25f : 1.0f;

        bf8 afr[4];
#pragma unroll
        for (int kt = 0; kt < 4; ++kt) {
            uint4 t = *(const uint4*)&wseg[(och + arow) * 64 + kt * 16 + agrp * 4];
            afr[kt] = __builtin_bit_cast(bf8, t);
        }

        f4 acc[4];
#pragma unroll
        for (int i = 0; i < 4; ++i) acc[i] = (f4){0.f, 0.f, 0.f, 0.f};
#pragma unroll
        for (int kt = 0; kt < 4; ++kt)
#pragma unroll
            for (int i = 0; i < 4; ++i)
                acc[i] = __builtin_amdgcn_mfma_f32_16x16x32_bf16(
                    afr[kt], __builtin_bit_cast(bf8, breg[kt][i]), acc[i], 0, 0, 0);

        unsigned short* ob = isgq ? gq_out : qkv_out;
        const int ostride = isgq ? 64 : 192;
#pragma unroll
        for (int r = 0; r < 4; ++r) {
            const int o = och + agrp * 4 + r;
            const float bs = bsrc[o] * bsc;
            const float v0 = acc[0][r] + bs, v1 = acc[1][r] + bs;
            const float v2 = acc[2][r] + bs, v3 = acc[3][r] + bs;
            *(uint2*)&ob[((long long)b * ostride + o) * NP + quad * 64 + arow * 4] =
                make_uint2(pack_bf2(v0, v1), pack_bf2(v2, v3));
        }
    }
}

// ---------------------------------------------------------------------------
// MFMA conv1x1 (gkv: f32 in -> f32 out); weights pre-packed. (r20-exact)
// ---------------------------------------------------------------------------
template<int C, int OT, int INBF, int OUTBF>
__global__ __launch_bounds__(256) void k_mfma_conv(
    const void* __restrict__ in0v, const unsigned* __restrict__ pw,
    const float* __restrict__ bias, void* __restrict__ outv,
    int np, long long ibs, int storeO)
{
    constexpr int KT = C / 32;
    const int tid  = threadIdx.x;
    const int lane = tid & 63, wid = tid >> 6;
    const int b    = blockIdx.z;
    const int obq  = blockIdx.y * (OT * 16);
    const int arow = lane & 15, agrp = lane >> 4;
    const int nquad = np >> 6;

    bf8 afr[OT][KT];
#pragma unroll
    for (int ot = 0; ot < OT; ++ot)
#pragma unroll
        for (int kt = 0; kt < KT; ++kt) {
            uint4 t = *(const uint4*)&pw[(obq + ot * 16 + arow) * (C / 2) + kt * 16 + agrp * 4];
            afr[ot][kt] = __builtin_bit_cast(bf8, t);
        }

    const float*          x0f = (const float*)in0v          + (long long)b * (INBF ? 0 : ibs);
    const unsigned short* x0h = (const unsigned short*)in0v + (long long)b * (INBF ? ibs : 0);

    const int quad = blockIdx.x * 4 + wid;
    if (quad >= nquad) return;
    const int p0 = quad * 64 + arow * 4;

    f4 acc[4][OT];
#pragma unroll
    for (int i = 0; i < 4; ++i)
#pragma unroll
        for (int ot = 0; ot < OT; ++ot) acc[i][ot] = (f4){0.f, 0.f, 0.f, 0.f};

#pragma unroll
    for (int kt = 0; kt < KT; ++kt) {
        const long long cbase = kt * 32 + agrp * 8;
        int uu[4][4];
#pragma unroll
        for (int jj = 0; jj < 4; ++jj) {
            if (INBF == 0) {
                float4 a0 = *(const float4*)&x0f[(cbase + 2 * jj) * np + p0];
                float4 a1 = *(const float4*)&x0f[(cbase + 2 * jj + 1) * np + p0];
                uu[0][jj] = (int)pack_bf2(a0.x, a1.x);
                uu[1][jj] = (int)pack_bf2(a0.y, a1.y);
                uu[2][jj] = (int)pack_bf2(a0.z, a1.z);
                uu[3][jj] = (int)pack_bf2(a0.w, a1.w);
            } else {
                ushort4 a0 = *(const ushort4*)&x0h[(cbase + 2 * jj) * np + p0];
                ushort4 a1 = *(const ushort4*)&x0h[(cbase + 2 * jj + 1) * np + p0];
                uu[0][jj] = (int)((unsigned)a0.x | ((unsigned)a1.x << 16));
                uu[1][jj] = (int)((unsigned)a0.y | ((unsigned)a1.y << 16));
                uu[2][jj] = (int)((unsigned)a0.z | ((unsigned)a1.z << 16));
                uu[3][jj] = (int)((unsigned)a0.w | ((unsigned)a1.w << 16));
            }
        }
#pragma unroll
        for (int i = 0; i < 4; ++i) {
            int4 ti = {uu[i][0], uu[i][1], uu[i][2], uu[i][3]};
            bf8 bfr = __builtin_bit_cast(bf8, ti);
#pragma unroll
            for (int ot = 0; ot < OT; ++ot)
                acc[i][ot] = __builtin_amdgcn_mfma_f32_16x16x32_bf16(afr[ot][kt], bfr, acc[i][ot], 0, 0, 0);
        }
    }

#pragma unroll
    for (int ot = 0; ot < OT; ++ot) {
#pragma unroll
        for (int r = 0; r < 4; ++r) {
            const int o = obq + ot * 16 + agrp * 4 + r;
            const float bs = bias[o];
            float4 v;
            v.x = acc[0][ot][r] + bs;
            v.y = acc[1][ot][r] + bs;
            v.z = acc[2][ot][r] + bs;
            v.w = acc[3][ot][r] + bs;
            const long long idx = ((long long)b * storeO + o) * np + p0;
            if (OUTBF == 0) {
                *(float4*)&((float*)outv)[idx] = v;
            } else {
                *(uint2*)&((unsigned short*)outv)[idx] =
                    make_uint2(pack_bf2(v.x, v.y), pack_bf2(v.z, v.w));
            }
        }
    }
}

// ---------------------------------------------------------------------------
// proj conv1x1, half-quad pixel split (am-pattern): wave covers 32 px,
// OT=4 (all 64 out-ch of its y-group) -> input reads per output unchanged,
// per-wave chain halved, 1152 blocks (4.5/CU).  bf16 in -> f32 out.
// ---------------------------------------------------------------------------
__global__ __launch_bounds__(256) void k_proj_half(
    const unsigned short* __restrict__ in, const unsigned* __restrict__ pw,
    const float* __restrict__ bias, float* __restrict__ outv)
{
    const int tid  = threadIdx.x;
    const int lane = tid & 63, wid = tid >> 6;
    const int b    = blockIdx.z;
    const int obq  = blockIdx.y * 64;
    const int arow = lane & 15, agrp = lane >> 4;

    const int hq   = blockIdx.x * 4 + wid;        // 0..287
    const int quad = hq >> 1, half = hq & 1;
    const int pp   = quad * 64 + arow * 4 + half * 2;

    bf8 afr[4][4];
#pragma unroll
    for (int ot = 0; ot < 4; ++ot)
#pragma unroll
        for (int kt = 0; kt < 4; ++kt) {
            uint4 t = *(const uint4*)&pw[PW_PROJ + (obq + ot * 16 + arow) * 64 + kt * 16 + agrp * 4];
            afr[ot][kt] = __builtin_bit_cast(bf8, t);
        }

    const unsigned short* x0h = in + (long long)b * 128 * NP;

    f4 acc[2][4];
#pragma unroll
    for (int i = 0; i < 2; ++i)
#pragma unroll
        for (int ot = 0; ot < 4; ++ot) acc[i][ot] = (f4){0.f, 0.f, 0.f, 0.f};

#pragma unroll
    for (int kt = 0; kt < 4; ++kt) {
        const long long cbase = kt * 32 + agrp * 8;
        int uu[2][4];
#pragma unroll
        for (int jj = 0; jj < 4; ++jj) {
            ushort2 a0 = *(const ushort2*)&x0h[(cbase + 2 * jj) * NP + pp];
            ushort2 a1 = *(const ushort2*)&x0h[(cbase + 2 * jj + 1) * NP + pp];
            uu[0][jj] = (int)((unsigned)a0.x | ((unsigned)a1.x << 16));
            uu[1][jj] = (int)((unsigned)a0.y | ((unsigned)a1.y << 16));
        }
#pragma unroll
        for (int i = 0; i < 2; ++i) {
            int4 ti = {uu[i][0], uu[i][1], uu[i][2], uu[i][3]};
            bf8 bfr = __builtin_bit_cast(bf8, ti);
#pragma unroll
            for (int ot = 0; ot < 4; ++ot)
                acc[i][ot] = __builtin_amdgcn_mfma_f32_16x16x32_bf16(afr[ot][kt], bfr, acc[i][ot], 0, 0, 0);
        }
    }

#pragma unroll
    for (int ot = 0; ot < 4; ++ot) {
#pragma unroll
        for (int r = 0; r < 4; ++r) {
            const int o = obq + ot * 16 + agrp * 4 + r;
            const float bs = bias[o];
            float2 v = make_float2(acc[0][ot][r] + bs, acc[1][ot][r] + bs);
            *(float2*)&outv[((long long)b * 128 + o) * NP + pp] = v;
        }
    }
}

// ---------------------------------------------------------------------------
// Merged am + attention kernel (r20-exact; verified 71.1 µs).
// ---------------------------------------------------------------------------
__global__ __launch_bounds__(256) void k_am_attn(
    const unsigned short* __restrict__ dw, const unsigned* __restrict__ pw,
    const float* __restrict__ b1v, const float* __restrict__ b2v,
    const unsigned short* __restrict__ q, const float* __restrict__ kv,
    unsigned short* __restrict__ hilo)
{
    __shared__ __align__(16) char smem[53760];
    const int bid = blockIdx.x;
    const int tid = threadIdx.x;
    const int lane = tid & 63, wid = tid >> 6;

    if (bid < 576) {
        // ================= am path (half-quad per wave) =================
        uint2* abuf = (uint2*)smem;
        const int arow = lane & 15, agrp = lane >> 4;

        const int hqi = bid * 4 + wid;
        const int b   = hqi / 288;
        const int t288 = hqi % 288;
        const int quad = t288 >> 1, half = t288 & 1;
        const int pp = quad * 64 + arow * 4 + half * 2;

        bf8 afr1[4][2], afr2[4][2];
#pragma unroll
        for (int ot = 0; ot < 4; ++ot)
#pragma unroll
            for (int kt = 0; kt < 2; ++kt) {
                uint4 t1 = *(const uint4*)&pw[PW_AM1 + (ot * 16 + arow) * 32 + kt * 16 + agrp * 4];
                uint4 t2 = *(const uint4*)&pw[PW_AM2 + (ot * 16 + arow) * 32 + kt * 16 + agrp * 4];
                afr1[ot][kt] = __builtin_bit_cast(bf8, t1);
                afr2[ot][kt] = __builtin_bit_cast(bf8, t2);
            }

        const unsigned short* xq = dw + (long long)b * (192ll * NP);
        const unsigned short* xk = xq + 64ll * NP;
        const unsigned short* xv = xq + 128ll * NP;

        f4 acc1[2][4];
#pragma unroll
        for (int i = 0; i < 2; ++i)
#pragma unroll
            for (int ot = 0; ot < 4; ++ot) acc1[i][ot] = (f4){0.f, 0.f, 0.f, 0.f};

#pragma unroll
        for (int kt = 0; kt < 2; ++kt) {
            const long long cbase = kt * 32 + agrp * 8;
            int uu[2][4];
#pragma unroll
            for (int jj = 0; jj < 4; ++jj) {
                ushort2 a0 = *(const ushort2*)&xq[(cbase + 2 * jj) * NP + pp];
                ushort2 a1 = *(const ushort2*)&xq[(cbase + 2 * jj + 1) * NP + pp];
                ushort2 y0 = *(const ushort2*)&xk[(cbase + 2 * jj) * NP + pp];
                ushort2 y1 = *(const ushort2*)&xk[(cbase + 2 * jj + 1) * NP + pp];
                uu[0][jj] = (int)pack_bf2(bf2f(a0.x) * bf2f(y0.x), bf2f(a1.x) * bf2f(y1.x));
                uu[1][jj] = (int)pack_bf2(bf2f(a0.y) * bf2f(y0.y), bf2f(a1.y) * bf2f(y1.y));
            }
#pragma unroll
            for (int i = 0; i < 2; ++i) {
                int4 ti = {uu[i][0], uu[i][1], uu[i][2], uu[i][3]};
                bf8 bfr = __builtin_bit_cast(bf8, ti);
#pragma unroll
                for (int ot = 0; ot < 4; ++ot)
                    acc1[i][ot] = __builtin_amdgcn_mfma_f32_16x16x32_bf16(afr1[ot][kt], bfr, acc1[i][ot], 0, 0, 0);
            }
        }

#pragma unroll
        for (int i = 0; i < 2; ++i)
#pragma unroll
            for (int ot = 0; ot < 4; ++ot) {
                const int ch0 = ot * 16 + agrp * 4;
                float v0 = acc1[i][ot][0] + b1v[ch0 + 0];
                float v1 = acc1[i][ot][1] + b1v[ch0 + 1];
                float v2 = acc1[i][ot][2] + b1v[ch0 + 2];
                float v3 = acc1[i][ot][3] + b1v[ch0 + 3];
                v0 = v0 / (1.f + __expf(-v0));
                v1 = v1 / (1.f + __expf(-v1));
                v2 = v2 / (1.f + __expf(-v2));
                v3 = v3 / (1.f + __expf(-v3));
                const int c2 = ot * 4 + agrp;
                abuf[wid * 512 + (arow * 2 + i) * 16 + (c2 ^ arow)] =
                    make_uint2(pack_bf2(v0, v1), pack_bf2(v2, v3));
            }

        f4 acc2[2][4];
#pragma unroll
        for (int i = 0; i < 2; ++i)
#pragma unroll
            for (int ot = 0; ot < 4; ++ot) acc2[i][ot] = (f4){0.f, 0.f, 0.f, 0.f};

#pragma unroll
        for (int kt = 0; kt < 2; ++kt) {
            const int bc2 = kt * 8 + agrp * 2;
#pragma unroll
            for (int i = 0; i < 2; ++i) {
                const uint2 rA = abuf[wid * 512 + (arow * 2 + i) * 16 + (bc2 ^ arow)];
                const uint2 rB = abuf[wid * 512 + (arow * 2 + i) * 16 + ((bc2 + 1) ^ arow)];
                int4 ti = make_int4((int)rA.x, (int)rA.y, (int)rB.x, (int)rB.y);
                bf8 bfr = __builtin_bit_cast(bf8, ti);
#pragma unroll
                for (int ot = 0; ot < 4; ++ot)
                    acc2[i][ot] = __builtin_amdgcn_mfma_f32_16x16x32_bf16(afr2[ot][kt], bfr, acc2[i][ot], 0, 0, 0);
            }
        }

#pragma unroll
        for (int ot = 0; ot < 4; ++ot) {
#pragma unroll
            for (int r = 0; r < 4; ++r) {
                const int o = ot * 16 + agrp * 4 + r;
                const float bs = b2v[o];
                ushort2 vv2 = *(const ushort2*)&xv[(long long)o * NP + pp];
                float h0 = tanhf((acc2[0][ot][r] + bs) * 0.25f) * bf2f(vv2.x);
                float h1 = tanhf((acc2[1][ot][r] + bs) * 0.25f) * bf2f(vv2.y);
                *(unsigned*)&hilo[((long long)b * 128 + o) * NP + pp] = pack_bf2(h0, h1);
            }
        }
        return;
    }

    // ================= attn path (r12-exact logic) =================
    int4*  klds4 = (int4*)smem;
    int4*  zlds4 = (int4*)(smem + 18432);
    int4*  vlds4 = (int4*)(smem + 18944);
    uint2* elds2 = (uint2*)(smem + 37376);

    const int flat = bid - 576;
    const int bx = flat % 72, bh = flat / 72;
    const int g = lane >> 4, qi = lane & 15;
    const int b = bh >> 2, h = bh & 3;

    const float* kbase = kv + ((long long)b * 128 + h * 16) * NPK;
    const float* vbase = kv + ((long long)b * 128 + 64 + h * 16) * NPK;

    for (int i = tid; i < 1152; i += 256) {
        const int key = i >> 1, dg = i & 1;
        const float* kp = kbase + (long long)(dg * 8) * NPK + key;
        int4 t;
        t.x = (int)pack_bf2(kp[0],       kp[NPK]);
        t.y = (int)pack_bf2(kp[2 * NPK], kp[3 * NPK]);
        t.z = (int)pack_bf2(kp[4 * NPK], kp[5 * NPK]);
        t.w = (int)pack_bf2(kp[6 * NPK], kp[7 * NPK]);
        klds4[(key >> 4) * 32 + dg * 16 + (key & 15)] = t;
    }
    for (int i = tid; i < 1152; i += 256) {
        const int t = i >> 6, l = i & 63;
        const float* vp = vbase + (long long)(l & 15) * NPK + t * 32 + (l >> 4) * 8;
        float4 a = *(const float4*)vp;
        float4 c = *(const float4*)(vp + 4);
        int4 tt;
        tt.x = (int)pack_bf2(a.x, a.y);
        tt.y = (int)pack_bf2(a.z, a.w);
        tt.z = (int)pack_bf2(c.x, c.y);
        tt.w = (int)pack_bf2(c.z, c.w);
        vlds4[i] = tt;
    }
    if (tid < 32) zlds4[tid] = make_int4(0, 0, 0, 0);
    __syncthreads();

    const int q0 = (bx * 4 + wid) * 32;
    const unsigned short* qcol = q + ((long long)b * 64 + h * 16) * NP + q0 + qi;
    int4 qv[2] = { make_int4(0, 0, 0, 0), make_int4(0, 0, 0, 0) };
    if (g < 2) {
#pragma unroll
        for (int s = 0; s < 2; ++s) {
            const unsigned short* qp = qcol + s * 16 + (long long)(g * 8) * NP;
            qv[s].x = (int)((unsigned)qp[0]          | ((unsigned)qp[(long long)NP]     << 16));
            qv[s].y = (int)((unsigned)qp[2ll * NP]   | ((unsigned)qp[3ll * NP]          << 16));
            qv[s].z = (int)((unsigned)qp[4ll * NP]   | ((unsigned)qp[5ll * NP]          << 16));
            qv[s].w = (int)((unsigned)qp[6ll * NP]   | ((unsigned)qp[7ll * NP]          << 16));
        }
    }

    f4 accp[2] = { (f4){0.f, 0.f, 0.f, 0.f}, (f4){0.f, 0.f, 0.f, 0.f} };
    float den[2] = { 0.f, 0.f };

    auto QKEXP = [&](int k2, int buf) {
#pragma unroll
        for (int tp = 0; tp < 2; ++tp) {
            const int4 kf = (lane < 32) ? klds4[(k2 * 2 + tp) * 32 + lane]
                                        : zlds4[lane & 31];
            const bf8 ka = __builtin_bit_cast(bf8, kf);
#pragma unroll
            for (int s = 0; s < 2; ++s) {
                f4 sa = __builtin_amdgcn_mfma_f32_16x16x32_bf16(
                    ka, __builtin_bit_cast(bf8, qv[s]), (f4){0.f, 0.f, 0.f, 0.f}, 0, 0, 0);
                const float e0 = __expf(sa[0]), e1 = __expf(sa[1]);
                const float e2 = __expf(sa[2]), e3 = __expf(sa[3]);
                den[s] += (e0 + e1) + (e2 + e3);
                elds2[buf * 1024 + wid * 256 + s * 128 + tp * 64 + g * 16 + qi] =
                    make_uint2(pack_bf2(e0, e1), pack_bf2(e2, e3));
            }
        }
    };
    auto PV = [&](int k2, int buf) {
        const bf8 va = __builtin_bit_cast(bf8, vlds4[k2 * 64 + lane]);
#pragma unroll
        for (int s = 0; s < 2; ++s) {
            const int base = buf * 1024 + wid * 256 + s * 128 + (g >> 1) * 64 + (g & 1) * 32 + qi;
            const uint2 r0 = elds2[base];
            const uint2 r1 = elds2[base + 16];
            int4 ti = make_int4((int)r0.x, (int)r0.y, (int)r1.x, (int)r1.y);
            accp[s] = __builtin_amdgcn_mfma_f32_16x16x32_bf16(
                va, __builtin_bit_cast(bf8, ti), accp[s], 0, 0, 0);
        }
    };

    QKEXP(0, 0);
    for (int k2 = 0; k2 < 17; ++k2) {
        QKEXP(k2 + 1, (k2 + 1) & 1);
        PV(k2, k2 & 1);
    }
    PV(17, 1);

#pragma unroll
    for (int s = 0; s < 2; ++s) {
        float d0 = den[s];
        d0 += __shfl_xor(d0, 16, 64);
        d0 += __shfl_xor(d0, 32, 64);
        const float inv = 1.0f / d0;
        unsigned short* op = hilo + ((long long)b * 128 + 64 + h * 16 + g * 4) * NP + q0 + s * 16 + qi;
#pragma unroll
        for (int r = 0; r < 4; ++r)
            op[(long long)r * NP] = f2bfu(accp[s][r] * inv);
    }
}

// ---------------------------------------------------------------------------
// depthwise 5x5, pad 2 — row-tiled LDS staging. (r20-exact)
// ---------------------------------------------------------------------------
__global__ __launch_bounds__(256) void k_dwconv5_lds(
    const unsigned short* __restrict__ in, const float* __restrict__ w,
    const float* __restrict__ bias, unsigned short* __restrict__ out, int ch_total)
{
    __shared__ __align__(16) float img[36 * WW];   // 13824 B
    const int tid = threadIdx.x;
    const int ch  = blockIdx.x;
    const int rt  = blockIdx.y;
    const int b   = blockIdx.z;
    const unsigned short* ip = in + ((long long)b * ch_total + ch) * NP;

    const int gr0 = rt * 32 - 2;
    for (int idx = tid; idx < 864; idx += 256) {
        const int rr = idx / 24, c4 = (idx - rr * 24) * 4;
        const int gr = gr0 + rr;
        float4 f;
        if (gr >= 0 && gr < HH) {
            const uint2 rv = *(const uint2*)&ip[gr * WW + c4];
            f.x = bflo(rv.x); f.y = bfhi(rv.x);
            f.z = bflo(rv.y); f.w = bfhi(rv.y);
        } else {
            f = make_float4(0.f, 0.f, 0.f, 0.f);
        }
        *(float4*)&img[rr * WW + c4] = f;
    }
    __syncthreads();

    const float* wp = w + ch * 25;
    float wr[25];
#pragma unroll
    for (int i = 0; i < 25; ++i) wr[i] = wp[i];
    const float bs = bias[ch];

    unsigned short* op = out + ((long long)b * ch_total + ch) * NP + rt * 32 * WW;

#pragma unroll
    for (int j = 0; j < 3; ++j) {
        const int q  = tid + 256 * j;
        const int yl = q / 24;
        const int x4 = (q - yl * 24) * 4;
        float o0 = bs, o1 = bs, o2 = bs, o3 = bs;
#pragma unroll
        for (int ky = 0; ky < 5; ++ky) {
            const float* row = &img[(yl + ky) * WW + x4];
            float4 mid = *(const float4*)row;
            float4 lf  = (x4 >= 4)      ? *(const float4*)(row - 4)
                                        : make_float4(0.f, 0.f, 0.f, 0.f);
            float4 rtv = (x4 + 4 < WW)  ? *(const float4*)(row + 4)
                                        : make_float4(0.f, 0.f, 0.f, 0.f);
            const float f0 = lf.z,  f1 = lf.w;
            const float f2 = mid.x, f3 = mid.y, f4v = mid.z, f5 = mid.w;
            const float f6 = rtv.x, f7 = rtv.y;
            const float w0 = wr[ky * 5 + 0], w1 = wr[ky * 5 + 1],
                        w2 = wr[ky * 5 + 2], w3 = wr[ky * 5 + 3],
                        w4 = wr[ky * 5 + 4];
            o0 = fmaf(w0, f0, o0); o0 = fmaf(w1, f1, o0); o0 = fmaf(w2, f2, o0);
            o0 = fmaf(w3, f3, o0); o0 = fmaf(w4, f4v, o0);
            o1 = fmaf(w0, f1, o1); o1 = fmaf(w1, f2, o1); o1 = fmaf(w2, f3, o1);
            o1 = fmaf(w3, f4v, o1); o1 = fmaf(w4, f5, o1);
            o2 = fmaf(w0, f2, o2); o2 = fmaf(w1, f3, o2); o2 = fmaf(w2, f4v, o2);
            o2 = fmaf(w3, f5, o2); o2 = fmaf(w4, f6, o2);
            o3 = fmaf(w0, f3, o3); o3 = fmaf(w1, f4v, o3); o3 = fmaf(w2, f5, o3);
            o3 = fmaf(w3, f6, o3); o3 = fmaf(w4, f7, o3);
        }
        *(uint2*)&op[yl * WW + x4] = make_uint2(pack_bf2(o0, o1), pack_bf2(o2, o3));
    }
}

// ---------------------------------------------------------------------------
// 4x4 average pool — float4 loads.  (r20-exact)
// ---------------------------------------------------------------------------
__global__ __launch_bounds__(256) void k_avgpool4(
    const float* __restrict__ in, float* __restrict__ out)
{
    int idx = blockIdx.x * 256 + threadIdx.x;
    int total = NB * 128 * NPK;
    if (idx >= total) return;
    int pw = idx % 24;
    int t  = idx / 24;
    int ph = t % 24;  t /= 24;
    int c  = t % 128;
    int b  = t / 128;
    const float* ip = in + ((long long)b * 128 + c) * NP + (ph * 4) * WW + pw * 4;
    float4 r0 = *(const float4*)(ip);
    float4 r1 = *(const float4*)(ip + WW);
    float4 r2 = *(const float4*)(ip + 2 * WW);
    float4 r3 = *(const float4*)(ip + 3 * WW);
    float s = ((r0.x + r0.y) + (r0.z + r0.w)) + ((r1.x + r1.y) + (r1.z + r1.w))
            + ((r2.x + r2.y) + (r2.z + r2.w)) + ((r3.x + r3.y) + (r3.z + r3.w));
    out[idx] = s * (1.0f / 16.0f);
}

// ---------------------------------------------------------------------------
extern "C" void kernel_launch(void* const* d_in, const int* in_sizes, int n_in,
                              void* d_out, int out_size, void* d_ws, size_t ws_size,
                              hipStream_t stream)
{
    const float* x      = (const float*)d_in[0];
    const float* qkv_w  = (const float*)d_in[1];
    const float* qkv_b  = (const float*)d_in[2];
    const float* dw_w   = (const float*)d_in[3];
    const float* dw_b   = (const float*)d_in[4];
    const float* am_w1  = (const float*)d_in[5];
    const float* am_b1  = (const float*)d_in[6];
    const float* am_w2  = (const float*)d_in[7];
    const float* am_b2  = (const float*)d_in[8];
    const float* gq_w   = (const float*)d_in[9];
    const float* gq_b   = (const float*)d_in[10];
    const float* gkv_w  = (const float*)d_in[11];
    const float* gkv_b  = (const float*)d_in[12];
    const float* proj_w = (const float*)d_in[13];
    const float* proj_b = (const float*)d_in[14];
    float* out = (float*)d_out;
    char* wsb = (char*)d_ws;

    unsigned short* t_qkv  = (unsigned short*)wsb;
    unsigned short* t_hilo = (unsigned short*)wsb;
    unsigned short* t_dw   = (unsigned short*)(wsb + 28311552);
    unsigned short* t_gq   = (unsigned short*)(wsb + 56623104);
    float*          t_pool = (float*)(wsb + 66060288);
    float*          t_gkv  = (float*)(wsb + 68419584);
    unsigned*       t_pw   = (unsigned*)(wsb + 70778880);

    // 0. pre-pack all conv weights (gq scaled 0.25)
    k_packw<<<dim3((PW_TOTAL + 255) / 256), 256, 0, stream>>>(
        qkv_w, gq_w, gkv_w, am_w1, am_w2, proj_w, t_pw);
    // 1. qkv (bf16) + gq (bf16, *0.25) from one LDS-staged read of x
    k_qkvgq<<<dim3(144, 1, NB), 256, 0, stream>>>(
        x, t_pw, qkv_b, gq_b, t_qkv, t_gq);
    // 2. depthwise 5x5 (bf16 in -> bf16 out), row-tiled
    k_dwconv5_lds<<<dim3(192, 3, NB), 256, 0, stream>>>(t_qkv, dw_w, dw_b, t_dw, 192);
    // 3. pooled = avgpool4(x)
    k_avgpool4<<<dim3((NB*128*NPK + 255)/256), 256, 0, stream>>>(x, t_pool);
    // 4. gkv = conv1x1(pooled)  f32 out
    k_mfma_conv<128,4,0,0><<<dim3(3,2,NB), 256, 0, stream>>>(
        t_pool, t_pw + PW_GKV, gkv_b, t_gkv, NPK, (long long)128 * NPK, 128);
    // 5+6. merged am (blocks 0..575, half-quad) + attention (576..2879)
    k_am_attn<<<dim3(2880), 256, 0, stream>>>(
        t_dw, t_pw, am_b1, am_b2, t_gq, t_gkv, t_hilo);
    // 7. out = proj conv1x1 (half-quad pixel split, OT=4)  f32 out
    k_proj_half<<<dim3(72, 2, NB), 256, 0, stream>>>(
        t_hilo, t_pw, proj_b, out);
}

// Round 23
// 144.153 us; speedup vs baseline: 1.0704x; 1.0392x over previous
//
#include <hip/hip_runtime.h>
#include <hip/hip_bf16.h>
#include <hip/hip_fp16.h>
#include <cstdint>

static constexpr int NB  = 8;
static constexpr int HH  = 96;
static constexpr int WW  = 96;
static constexpr int NP  = 9216;   // 96*96
static constexpr int NPK = 576;    // 24*24

using bf8 = __attribute__((ext_vector_type(8))) short;
using f4  = __attribute__((ext_vector_type(4))) float;

__device__ __forceinline__ unsigned pack_bf2(float a, float b) {
    __hip_bfloat162 h = __float22bfloat162_rn(make_float2(a, b));
    unsigned u; __builtin_memcpy(&u, &h, 4);
    return u;
}
__device__ __forceinline__ unsigned short f2bfu(float f) {
    __hip_bfloat16 h = __float2bfloat16(f);
    unsigned short u; __builtin_memcpy(&u, &h, 2);
    return u;
}
__device__ __forceinline__ float bf2f(unsigned short u) {
    unsigned v = (unsigned)u << 16;
    float f; __builtin_memcpy(&f, &v, 4);
    return f;
}
__device__ __forceinline__ float bflo(unsigned p) {
    unsigned v = p << 16; float f; __builtin_memcpy(&f, &v, 4); return f;
}
__device__ __forceinline__ float bfhi(unsigned p) {
    unsigned v = p & 0xffff0000u; float f; __builtin_memcpy(&f, &v, 4); return f;
}

// packed-weight segment offsets (uints)
static constexpr int PW_QKV  = 0;       // 192*64
static constexpr int PW_GQ   = 12288;   // 64*64  (scaled 0.25)
static constexpr int PW_GKV  = 16384;   // 128*64
static constexpr int PW_AM1  = 24576;   // 64*32
static constexpr int PW_AM2  = 26624;   // 64*32
static constexpr int PW_PROJ = 28672;   // 128*64
static constexpr int PW_TOTAL= 36864;

// ---------------------------------------------------------------------------
// One-time weight pre-pack (gq segment scaled 0.25).
// ---------------------------------------------------------------------------
__global__ __launch_bounds__(256) void k_packw(
    const float* __restrict__ qkv_w, const float* __restrict__ gq_w,
    const float* __restrict__ gkv_w, const float* __restrict__ am_w1,
    const float* __restrict__ am_w2, const float* __restrict__ proj_w,
    unsigned* __restrict__ pw)
{
    const int idx = blockIdx.x * 256 + threadIdx.x;
    if (idx >= PW_TOTAL) return;
    const float* src; int j2; float sc = 1.0f;
    if (idx < PW_GQ)          { src = qkv_w;  j2 = (idx - PW_QKV) * 2; }
    else if (idx < PW_GKV)    { src = gq_w;   j2 = (idx - PW_GQ) * 2;  sc = 0.25f; }
    else if (idx < PW_AM1)    { src = gkv_w;  j2 = (idx - PW_GKV) * 2; }
    else if (idx < PW_AM2)    { src = am_w1;  j2 = (idx - PW_AM1) * 2; }
    else if (idx < PW_PROJ)   { src = am_w2;  j2 = (idx - PW_AM2) * 2; }
    else                      { src = proj_w; j2 = (idx - PW_PROJ) * 2; }
    pw[idx] = pack_bf2(src[j2] * sc, src[j2 + 1] * sc);
}

// ---------------------------------------------------------------------------
// Fused qkv+gq conv1x1 with LDS-staged x; weights pre-packed. (r20-exact)
// ---------------------------------------------------------------------------
__global__ __launch_bounds__(256) void k_qkvgq(
    const float* __restrict__ x, const unsigned* __restrict__ pw,
    const float* __restrict__ qkv_b, const float* __restrict__ gq_b,
    unsigned short* __restrict__ qkv_out,   // bf16 (B,192,NP)
    unsigned short* __restrict__ gq_out)    // bf16 (B,64,NP), pre-scaled 0.25
{
    __shared__ __align__(16) unsigned xl[64 * 64];   // 16KB
    const int tid  = threadIdx.x;
    const int lane = tid & 63, wid = tid >> 6;
    const int quad = blockIdx.x, b = blockIdx.z;
    const int arow = lane & 15, agrp = lane >> 4;

    const float* xb = x + (long long)b * 128 * NP + quad * 64;

#pragma unroll
    for (int it = 0; it < 4; ++it) {
        const int task = tid + 256 * it;
        const int cp = task >> 4, pq = task & 15;
        float4 a = *(const float4*)&xb[(long long)(2 * cp) * NP + pq * 4];
        float4 c = *(const float4*)&xb[(long long)(2 * cp + 1) * NP + pq * 4];
        const int cps = cp ^ ((pq & 7) << 2);
        xl[(pq * 4 + 0) * 64 + cps] = pack_bf2(a.x, c.x);
        xl[(pq * 4 + 1) * 64 + cps] = pack_bf2(a.y, c.y);
        xl[(pq * 4 + 2) * 64 + cps] = pack_bf2(a.z, c.z);
        xl[(pq * 4 + 3) * 64 + cps] = pack_bf2(a.w, c.w);
    }
    __syncthreads();

    uint4 breg[4][4];
#pragma unroll
    for (int kt = 0; kt < 4; ++kt)
#pragma unroll
        for (int i = 0; i < 4; ++i) {
            const int px = arow * 4 + i;
            const int cp = (kt * 16 + agrp * 4) ^ ((arow & 7) << 2);
            breg[kt][i] = *(const uint4*)&xl[px * 64 + cp];
        }

    for (int gi = 0; gi < 4; ++gi) {
        const int grp = wid + gi * 4;
        const bool isgq = grp >= 12;
        const int och = (isgq ? grp - 12 : grp) * 16;
        const unsigned* wseg = pw + (isgq ? PW_GQ : PW_QKV);
        const float* bsrc = isgq ? gq_b : qkv_b;
        const float bsc = isgq ? 0.25f : 1.0f;

        bf8 afr[4];
#pragma unroll
        for (int kt = 0; kt < 4; ++kt) {
            uint4 t = *(const uint4*)&wseg[(och + arow) * 64 + kt * 16 + agrp * 4];
            afr[kt] = __builtin_bit_cast(bf8, t);
        }

        f4 acc[4];
#pragma unroll
        for (int i = 0; i < 4; ++i) acc[i] = (f4){0.f, 0.f, 0.f, 0.f};
#pragma unroll
        for (int kt = 0; kt < 4; ++kt)
#pragma unroll
            for (int i = 0; i < 4; ++i)
                acc[i] = __builtin_amdgcn_mfma_f32_16x16x32_bf16(
                    afr[kt], __builtin_bit_cast(bf8, breg[kt][i]), acc[i], 0, 0, 0);

        unsigned short* ob = isgq ? gq_out : qkv_out;
        const int ostride = isgq ? 64 : 192;
#pragma unroll
        for (int r = 0; r < 4; ++r) {
            const int o = och + agrp * 4 + r;
            const float bs = bsrc[o] * bsc;
            const float v0 = acc[0][r] + bs, v1 = acc[1][r] + bs;
            const float v2 = acc[2][r] + bs, v3 = acc[3][r] + bs;
            *(uint2*)&ob[((long long)b * ostride + o) * NP + quad * 64 + arow * 4] =
                make_uint2(pack_bf2(v0, v1), pack_bf2(v2, v3));
        }
    }
}

// ---------------------------------------------------------------------------
// MFMA conv1x1 (gkv f32->f32, proj bf16->f32); weights pre-packed. (r20-exact)
// ---------------------------------------------------------------------------
template<int C, int OT, int INBF, int OUTBF>
__global__ __launch_bounds__(256) void k_mfma_conv(
    const void* __restrict__ in0v, const unsigned* __restrict__ pw,
    const float* __restrict__ bias, void* __restrict__ outv,
    int np, long long ibs, int storeO)
{
    constexpr int KT = C / 32;
    const int tid  = threadIdx.x;
    const int lane = tid & 63, wid = tid >> 6;
    const int b    = blockIdx.z;
    const int obq  = blockIdx.y * (OT * 16);
    const int arow = lane & 15, agrp = lane >> 4;
    const int nquad = np >> 6;

    bf8 afr[OT][KT];
#pragma unroll
    for (int ot = 0; ot < OT; ++ot)
#pragma unroll
        for (int kt = 0; kt < KT; ++kt) {
            uint4 t = *(const uint4*)&pw[(obq + ot * 16 + arow) * (C / 2) + kt * 16 + agrp * 4];
            afr[ot][kt] = __builtin_bit_cast(bf8, t);
        }

    const float*          x0f = (const float*)in0v          + (long long)b * (INBF ? 0 : ibs);
    const unsigned short* x0h = (const unsigned short*)in0v + (long long)b * (INBF ? ibs : 0);

    const int quad = blockIdx.x * 4 + wid;
    if (quad >= nquad) return;
    const int p0 = quad * 64 + arow * 4;

    f4 acc[4][OT];
#pragma unroll
    for (int i = 0; i < 4; ++i)
#pragma unroll
        for (int ot = 0; ot < OT; ++ot) acc[i][ot] = (f4){0.f, 0.f, 0.f, 0.f};

#pragma unroll
    for (int kt = 0; kt < KT; ++kt) {
        const long long cbase = kt * 32 + agrp * 8;
        int uu[4][4];
#pragma unroll
        for (int jj = 0; jj < 4; ++jj) {
            if (INBF == 0) {
                float4 a0 = *(const float4*)&x0f[(cbase + 2 * jj) * np + p0];
                float4 a1 = *(const float4*)&x0f[(cbase + 2 * jj + 1) * np + p0];
                uu[0][jj] = (int)pack_bf2(a0.x, a1.x);
                uu[1][jj] = (int)pack_bf2(a0.y, a1.y);
                uu[2][jj] = (int)pack_bf2(a0.z, a1.z);
                uu[3][jj] = (int)pack_bf2(a0.w, a1.w);
            } else {
                ushort4 a0 = *(const ushort4*)&x0h[(cbase + 2 * jj) * np + p0];
                ushort4 a1 = *(const ushort4*)&x0h[(cbase + 2 * jj + 1) * np + p0];
                uu[0][jj] = (int)((unsigned)a0.x | ((unsigned)a1.x << 16));
                uu[1][jj] = (int)((unsigned)a0.y | ((unsigned)a1.y << 16));
                uu[2][jj] = (int)((unsigned)a0.z | ((unsigned)a1.z << 16));
                uu[3][jj] = (int)((unsigned)a0.w | ((unsigned)a1.w << 16));
            }
        }
#pragma unroll
        for (int i = 0; i < 4; ++i) {
            int4 ti = {uu[i][0], uu[i][1], uu[i][2], uu[i][3]};
            bf8 bfr = __builtin_bit_cast(bf8, ti);
#pragma unroll
            for (int ot = 0; ot < OT; ++ot)
                acc[i][ot] = __builtin_amdgcn_mfma_f32_16x16x32_bf16(afr[ot][kt], bfr, acc[i][ot], 0, 0, 0);
        }
    }

#pragma unroll
    for (int ot = 0; ot < OT; ++ot) {
#pragma unroll
        for (int r = 0; r < 4; ++r) {
            const int o = obq + ot * 16 + agrp * 4 + r;
            const float bs = bias[o];
            float4 v;
            v.x = acc[0][ot][r] + bs;
            v.y = acc[1][ot][r] + bs;
            v.z = acc[2][ot][r] + bs;
            v.w = acc[3][ot][r] + bs;
            const long long idx = ((long long)b * storeO + o) * np + p0;
            if (OUTBF == 0) {
                *(float4*)&((float*)outv)[idx] = v;
            } else {
                *(uint2*)&((unsigned short*)outv)[idx] =
                    make_uint2(pack_bf2(v.x, v.y), pack_bf2(v.z, v.w));
            }
        }
    }
}

// ---------------------------------------------------------------------------
// Merged am + attention kernel (r20-exact; verified 71.1 µs).
// ---------------------------------------------------------------------------
__global__ __launch_bounds__(256) void k_am_attn(
    const unsigned short* __restrict__ dw, const unsigned* __restrict__ pw,
    const float* __restrict__ b1v, const float* __restrict__ b2v,
    const unsigned short* __restrict__ q, const float* __restrict__ kv,
    unsigned short* __restrict__ hilo)
{
    __shared__ __align__(16) char smem[53760];
    const int bid = blockIdx.x;
    const int tid = threadIdx.x;
    const int lane = tid & 63, wid = tid >> 6;

    if (bid < 576) {
        // ================= am path (half-quad per wave) =================
        uint2* abuf = (uint2*)smem;
        const int arow = lane & 15, agrp = lane >> 4;

        const int hqi = bid * 4 + wid;
        const int b   = hqi / 288;
        const int t288 = hqi % 288;
        const int quad = t288 >> 1, half = t288 & 1;
        const int pp = quad * 64 + arow * 4 + half * 2;

        bf8 afr1[4][2], afr2[4][2];
#pragma unroll
        for (int ot = 0; ot < 4; ++ot)
#pragma unroll
            for (int kt = 0; kt < 2; ++kt) {
                uint4 t1 = *(const uint4*)&pw[PW_AM1 + (ot * 16 + arow) * 32 + kt * 16 + agrp * 4];
                uint4 t2 = *(const uint4*)&pw[PW_AM2 + (ot * 16 + arow) * 32 + kt * 16 + agrp * 4];
                afr1[ot][kt] = __builtin_bit_cast(bf8, t1);
                afr2[ot][kt] = __builtin_bit_cast(bf8, t2);
            }

        const unsigned short* xq = dw + (long long)b * (192ll * NP);
        const unsigned short* xk = xq + 64ll * NP;
        const unsigned short* xv = xq + 128ll * NP;

        f4 acc1[2][4];
#pragma unroll
        for (int i = 0; i < 2; ++i)
#pragma unroll
            for (int ot = 0; ot < 4; ++ot) acc1[i][ot] = (f4){0.f, 0.f, 0.f, 0.f};

#pragma unroll
        for (int kt = 0; kt < 2; ++kt) {
            const long long cbase = kt * 32 + agrp * 8;
            int uu[2][4];
#pragma unroll
            for (int jj = 0; jj < 4; ++jj) {
                ushort2 a0 = *(const ushort2*)&xq[(cbase + 2 * jj) * NP + pp];
                ushort2 a1 = *(const ushort2*)&xq[(cbase + 2 * jj + 1) * NP + pp];
                ushort2 y0 = *(const ushort2*)&xk[(cbase + 2 * jj) * NP + pp];
                ushort2 y1 = *(const ushort2*)&xk[(cbase + 2 * jj + 1) * NP + pp];
                uu[0][jj] = (int)pack_bf2(bf2f(a0.x) * bf2f(y0.x), bf2f(a1.x) * bf2f(y1.x));
                uu[1][jj] = (int)pack_bf2(bf2f(a0.y) * bf2f(y0.y), bf2f(a1.y) * bf2f(y1.y));
            }
#pragma unroll
            for (int i = 0; i < 2; ++i) {
                int4 ti = {uu[i][0], uu[i][1], uu[i][2], uu[i][3]};
                bf8 bfr = __builtin_bit_cast(bf8, ti);
#pragma unroll
                for (int ot = 0; ot < 4; ++ot)
                    acc1[i][ot] = __builtin_amdgcn_mfma_f32_16x16x32_bf16(afr1[ot][kt], bfr, acc1[i][ot], 0, 0, 0);
            }
        }

#pragma unroll
        for (int i = 0; i < 2; ++i)
#pragma unroll
            for (int ot = 0; ot < 4; ++ot) {
                const int ch0 = ot * 16 + agrp * 4;
                float v0 = acc1[i][ot][0] + b1v[ch0 + 0];
                float v1 = acc1[i][ot][1] + b1v[ch0 + 1];
                float v2 = acc1[i][ot][2] + b1v[ch0 + 2];
                float v3 = acc1[i][ot][3] + b1v[ch0 + 3];
                v0 = v0 / (1.f + __expf(-v0));
                v1 = v1 / (1.f + __expf(-v1));
                v2 = v2 / (1.f + __expf(-v2));
                v3 = v3 / (1.f + __expf(-v3));
                const int c2 = ot * 4 + agrp;
                abuf[wid * 512 + (arow * 2 + i) * 16 + (c2 ^ arow)] =
                    make_uint2(pack_bf2(v0, v1), pack_bf2(v2, v3));
            }

        f4 acc2[2][4];
#pragma unroll
        for (int i = 0; i < 2; ++i)
#pragma unroll
            for (int ot = 0; ot < 4; ++ot) acc2[i][ot] = (f4){0.f, 0.f, 0.f, 0.f};

#pragma unroll
        for (int kt = 0; kt < 2; ++kt) {
            const int bc2 = kt * 8 + agrp * 2;
#pragma unroll
            for (int i = 0; i < 2; ++i) {
                const uint2 rA = abuf[wid * 512 + (arow * 2 + i) * 16 + (bc2 ^ arow)];
                const uint2 rB = abuf[wid * 512 + (arow * 2 + i) * 16 + ((bc2 + 1) ^ arow)];
                int4 ti = make_int4((int)rA.x, (int)rA.y, (int)rB.x, (int)rB.y);
                bf8 bfr = __builtin_bit_cast(bf8, ti);
#pragma unroll
                for (int ot = 0; ot < 4; ++ot)
                    acc2[i][ot] = __builtin_amdgcn_mfma_f32_16x16x32_bf16(afr2[ot][kt], bfr, acc2[i][ot], 0, 0, 0);
            }
        }

#pragma unroll
        for (int ot = 0; ot < 4; ++ot) {
#pragma unroll
            for (int r = 0; r < 4; ++r) {
                const int o = ot * 16 + agrp * 4 + r;
                const float bs = b2v[o];
                ushort2 vv2 = *(const ushort2*)&xv[(long long)o * NP + pp];
                float h0 = tanhf((acc2[0][ot][r] + bs) * 0.25f) * bf2f(vv2.x);
                float h1 = tanhf((acc2[1][ot][r] + bs) * 0.25f) * bf2f(vv2.y);
                *(unsigned*)&hilo[((long long)b * 128 + o) * NP + pp] = pack_bf2(h0, h1);
            }
        }
        return;
    }

    // ================= attn path (r12-exact logic) =================
    int4*  klds4 = (int4*)smem;
    int4*  zlds4 = (int4*)(smem + 18432);
    int4*  vlds4 = (int4*)(smem + 18944);
    uint2* elds2 = (uint2*)(smem + 37376);

    const int flat = bid - 576;
    const int bx = flat % 72, bh = flat / 72;
    const int g = lane >> 4, qi = lane & 15;
    const int b = bh >> 2, h = bh & 3;

    const float* kbase = kv + ((long long)b * 128 + h * 16) * NPK;
    const float* vbase = kv + ((long long)b * 128 + 64 + h * 16) * NPK;

    for (int i = tid; i < 1152; i += 256) {
        const int key = i >> 1, dg = i & 1;
        const float* kp = kbase + (long long)(dg * 8) * NPK + key;
        int4 t;
        t.x = (int)pack_bf2(kp[0],       kp[NPK]);
        t.y = (int)pack_bf2(kp[2 * NPK], kp[3 * NPK]);
        t.z = (int)pack_bf2(kp[4 * NPK], kp[5 * NPK]);
        t.w = (int)pack_bf2(kp[6 * NPK], kp[7 * NPK]);
        klds4[(key >> 4) * 32 + dg * 16 + (key & 15)] = t;
    }
    for (int i = tid; i < 1152; i += 256) {
        const int t = i >> 6, l = i & 63;
        const float* vp = vbase + (long long)(l & 15) * NPK + t * 32 + (l >> 4) * 8;
        float4 a = *(const float4*)vp;
        float4 c = *(const float4*)(vp + 4);
        int4 tt;
        tt.x = (int)pack_bf2(a.x, a.y);
        tt.y = (int)pack_bf2(a.z, a.w);
        tt.z = (int)pack_bf2(c.x, c.y);
        tt.w = (int)pack_bf2(c.z, c.w);
        vlds4[i] = tt;
    }
    if (tid < 32) zlds4[tid] = make_int4(0, 0, 0, 0);
    __syncthreads();

    const int q0 = (bx * 4 + wid) * 32;
    const unsigned short* qcol = q + ((long long)b * 64 + h * 16) * NP + q0 + qi;
    int4 qv[2] = { make_int4(0, 0, 0, 0), make_int4(0, 0, 0, 0) };
    if (g < 2) {
#pragma unroll
        for (int s = 0; s < 2; ++s) {
            const unsigned short* qp = qcol + s * 16 + (long long)(g * 8) * NP;
            qv[s].x = (int)((unsigned)qp[0]          | ((unsigned)qp[(long long)NP]     << 16));
            qv[s].y = (int)((unsigned)qp[2ll * NP]   | ((unsigned)qp[3ll * NP]          << 16));
            qv[s].z = (int)((unsigned)qp[4ll * NP]   | ((unsigned)qp[5ll * NP]          << 16));
            qv[s].w = (int)((unsigned)qp[6ll * NP]   | ((unsigned)qp[7ll * NP]          << 16));
        }
    }

    f4 accp[2] = { (f4){0.f, 0.f, 0.f, 0.f}, (f4){0.f, 0.f, 0.f, 0.f} };
    float den[2] = { 0.f, 0.f };

    auto QKEXP = [&](int k2, int buf) {
#pragma unroll
        for (int tp = 0; tp < 2; ++tp) {
            const int4 kf = (lane < 32) ? klds4[(k2 * 2 + tp) * 32 + lane]
                                        : zlds4[lane & 31];
            const bf8 ka = __builtin_bit_cast(bf8, kf);
#pragma unroll
            for (int s = 0; s < 2; ++s) {
                f4 sa = __builtin_amdgcn_mfma_f32_16x16x32_bf16(
                    ka, __builtin_bit_cast(bf8, qv[s]), (f4){0.f, 0.f, 0.f, 0.f}, 0, 0, 0);
                const float e0 = __expf(sa[0]), e1 = __expf(sa[1]);
                const float e2 = __expf(sa[2]), e3 = __expf(sa[3]);
                den[s] += (e0 + e1) + (e2 + e3);
                elds2[buf * 1024 + wid * 256 + s * 128 + tp * 64 + g * 16 + qi] =
                    make_uint2(pack_bf2(e0, e1), pack_bf2(e2, e3));
            }
        }
    };
    auto PV = [&](int k2, int buf) {
        const bf8 va = __builtin_bit_cast(bf8, vlds4[k2 * 64 + lane]);
#pragma unroll
        for (int s = 0; s < 2; ++s) {
            const int base = buf * 1024 + wid * 256 + s * 128 + (g >> 1) * 64 + (g & 1) * 32 + qi;
            const uint2 r0 = elds2[base];
            const uint2 r1 = elds2[base + 16];
            int4 ti = make_int4((int)r0.x, (int)r0.y, (int)r1.x, (int)r1.y);
            accp[s] = __builtin_amdgcn_mfma_f32_16x16x32_bf16(
                va, __builtin_bit_cast(bf8, ti), accp[s], 0, 0, 0);
        }
    };

    QKEXP(0, 0);
    for (int k2 = 0; k2 < 17; ++k2) {
        QKEXP(k2 + 1, (k2 + 1) & 1);
        PV(k2, k2 & 1);
    }
    PV(17, 1);

#pragma unroll
    for (int s = 0; s < 2; ++s) {
        float d0 = den[s];
        d0 += __shfl_xor(d0, 16, 64);
        d0 += __shfl_xor(d0, 32, 64);
        const float inv = 1.0f / d0;
        unsigned short* op = hilo + ((long long)b * 128 + 64 + h * 16 + g * 4) * NP + q0 + s * 16 + qi;
#pragma unroll
        for (int r = 0; r < 4; ++r)
            op[(long long)r * NP] = f2bfu(accp[s][r] * inv);
    }
}

// ---------------------------------------------------------------------------
// depthwise 5x5, pad 2 — row-tiled LDS staging. (r20-exact)
// ---------------------------------------------------------------------------
__global__ __launch_bounds__(256) void k_dwconv5_lds(
    const unsigned short* __restrict__ in, const float* __restrict__ w,
    const float* __restrict__ bias, unsigned short* __restrict__ out, int ch_total)
{
    __shared__ __align__(16) float img[36 * WW];   // 13824 B
    const int tid = threadIdx.x;
    const int ch  = blockIdx.x;
    const int rt  = blockIdx.y;
    const int b   = blockIdx.z;
    const unsigned short* ip = in + ((long long)b * ch_total + ch) * NP;

    const int gr0 = rt * 32 - 2;
    for (int idx = tid; idx < 864; idx += 256) {
        const int rr = idx / 24, c4 = (idx - rr * 24) * 4;
        const int gr = gr0 + rr;
        float4 f;
        if (gr >= 0 && gr < HH) {
            const uint2 rv = *(const uint2*)&ip[gr * WW + c4];
            f.x = bflo(rv.x); f.y = bfhi(rv.x);
            f.z = bflo(rv.y); f.w = bfhi(rv.y);
        } else {
            f = make_float4(0.f, 0.f, 0.f, 0.f);
        }
        *(float4*)&img[rr * WW + c4] = f;
    }
    __syncthreads();

    const float* wp = w + ch * 25;
    float wr[25];
#pragma unroll
    for (int i = 0; i < 25; ++i) wr[i] = wp[i];
    const float bs = bias[ch];

    unsigned short* op = out + ((long long)b * ch_total + ch) * NP + rt * 32 * WW;

#pragma unroll
    for (int j = 0; j < 3; ++j) {
        const int q  = tid + 256 * j;
        const int yl = q / 24;
        const int x4 = (q - yl * 24) * 4;
        float o0 = bs, o1 = bs, o2 = bs, o3 = bs;
#pragma unroll
        for (int ky = 0; ky < 5; ++ky) {
            const float* row = &img[(yl + ky) * WW + x4];
            float4 mid = *(const float4*)row;
            float4 lf  = (x4 >= 4)      ? *(const float4*)(row - 4)
                                        : make_float4(0.f, 0.f, 0.f, 0.f);
            float4 rtv = (x4 + 4 < WW)  ? *(const float4*)(row + 4)
                                        : make_float4(0.f, 0.f, 0.f, 0.f);
            const float f0 = lf.z,  f1 = lf.w;
            const float f2 = mid.x, f3 = mid.y, f4v = mid.z, f5 = mid.w;
            const float f6 = rtv.x, f7 = rtv.y;
            const float w0 = wr[ky * 5 + 0], w1 = wr[ky * 5 + 1],
                        w2 = wr[ky * 5 + 2], w3 = wr[ky * 5 + 3],
                        w4 = wr[ky * 5 + 4];
            o0 = fmaf(w0, f0, o0); o0 = fmaf(w1, f1, o0); o0 = fmaf(w2, f2, o0);
            o0 = fmaf(w3, f3, o0); o0 = fmaf(w4, f4v, o0);
            o1 = fmaf(w0, f1, o1); o1 = fmaf(w1, f2, o1); o1 = fmaf(w2, f3, o1);
            o1 = fmaf(w3, f4v, o1); o1 = fmaf(w4, f5, o1);
            o2 = fmaf(w0, f2, o2); o2 = fmaf(w1, f3, o2); o2 = fmaf(w2, f4v, o2);
            o2 = fmaf(w3, f5, o2); o2 = fmaf(w4, f6, o2);
            o3 = fmaf(w0, f3, o3); o3 = fmaf(w1, f4v, o3); o3 = fmaf(w2, f5, o3);
            o3 = fmaf(w3, f6, o3); o3 = fmaf(w4, f7, o3);
        }
        *(uint2*)&op[yl * WW + x4] = make_uint2(pack_bf2(o0, o1), pack_bf2(o2, o3));
    }
}

// ---------------------------------------------------------------------------
// 4x4 average pool — float4 loads.  (r20-exact)
// ---------------------------------------------------------------------------
__global__ __launch_bounds__(256) void k_avgpool4(
    const float* __restrict__ in, float* __restrict__ out)
{
    int idx = blockIdx.x * 256 + threadIdx.x;
    int total = NB * 128 * NPK;
    if (idx >= total) return;
    int pw = idx % 24;
    int t  = idx / 24;
    int ph = t % 24;  t /= 24;
    int c  = t % 128;
    int b  = t / 128;
    const float* ip = in + ((long long)b * 128 + c) * NP + (ph * 4) * WW + pw * 4;
    float4 r0 = *(const float4*)(ip);
    float4 r1 = *(const float4*)(ip + WW);
    float4 r2 = *(const float4*)(ip + 2 * WW);
    float4 r3 = *(const float4*)(ip + 3 * WW);
    float s = ((r0.x + r0.y) + (r0.z + r0.w)) + ((r1.x + r1.y) + (r1.z + r1.w))
            + ((r2.x + r2.y) + (r2.z + r2.w)) + ((r3.x + r3.y) + (r3.z + r3.w));
    out[idx] = s * (1.0f / 16.0f);
}

// ---------------------------------------------------------------------------
extern "C" void kernel_launch(void* const* d_in, const int* in_sizes, int n_in,
                              void* d_out, int out_size, void* d_ws, size_t ws_size,
                              hipStream_t stream)
{
    const float* x      = (const float*)d_in[0];
    const float* qkv_w  = (const float*)d_in[1];
    const float* qkv_b  = (const float*)d_in[2];
    const float* dw_w   = (const float*)d_in[3];
    const float* dw_b   = (const float*)d_in[4];
    const float* am_w1  = (const float*)d_in[5];
    const float* am_b1  = (const float*)d_in[6];
    const float* am_w2  = (const float*)d_in[7];
    const float* am_b2  = (const float*)d_in[8];
    const float* gq_w   = (const float*)d_in[9];
    const float* gq_b   = (const float*)d_in[10];
    const float* gkv_w  = (const float*)d_in[11];
    const float* gkv_b  = (const float*)d_in[12];
    const float* proj_w = (const float*)d_in[13];
    const float* proj_b = (const float*)d_in[14];
    float* out = (float*)d_out;
    char* wsb = (char*)d_ws;

    unsigned short* t_qkv  = (unsigned short*)wsb;
    unsigned short* t_hilo = (unsigned short*)wsb;
    unsigned short* t_dw   = (unsigned short*)(wsb + 28311552);
    unsigned short* t_gq   = (unsigned short*)(wsb + 56623104);
    float*          t_pool = (float*)(wsb + 66060288);
    float*          t_gkv  = (float*)(wsb + 68419584);
    unsigned*       t_pw   = (unsigned*)(wsb + 70778880);

    // 0. pre-pack all conv weights (gq scaled 0.25)
    k_packw<<<dim3((PW_TOTAL + 255) / 256), 256, 0, stream>>>(
        qkv_w, gq_w, gkv_w, am_w1, am_w2, proj_w, t_pw);
    // 1. qkv (bf16) + gq (bf16, *0.25) from one LDS-staged read of x
    k_qkvgq<<<dim3(144, 1, NB), 256, 0, stream>>>(
        x, t_pw, qkv_b, gq_b, t_qkv, t_gq);
    // 2. depthwise 5x5 (bf16 in -> bf16 out), row-tiled
    k_dwconv5_lds<<<dim3(192, 3, NB), 256, 0, stream>>>(t_qkv, dw_w, dw_b, t_dw, 192);
    // 3. pooled = avgpool4(x)
    k_avgpool4<<<dim3((NB*128*NPK + 255)/256), 256, 0, stream>>>(x, t_pool);
    // 4. gkv = conv1x1(pooled)  f32 out
    k_mfma_conv<128,4,0,0><<<dim3(3,2,NB), 256, 0, stream>>>(
        t_pool, t_pw + PW_GKV, gkv_b, t_gkv, NPK, (long long)128 * NPK, 128);
    // 5+6. merged am (blocks 0..575, half-quad) + attention (576..2879)
    k_am_attn<<<dim3(2880), 256, 0, stream>>>(
        t_dw, t_pw, am_b1, am_b2, t_gq, t_gkv, t_hilo);
    // 7. out = conv1x1(hilo bf16, proj_w), OT=4  (f32 out)
    k_mfma_conv<128,4,1,0><<<dim3(36,2,NB), 256, 0, stream>>>(
        t_hilo, t_pw + PW_PROJ, proj_b, out, NP, (long long)128 * NP, 128);
}